// Round 1
// baseline (2718.326 us; speedup 1.0000x reference)
//
#include <hip/hip_runtime.h>
#include <math.h>

// Problem constants
constexpr int B_ = 64, N_ = 1024, M_ = 32, T_ = 8;
constexpr int OUT_ = 1000, NSO_ = 256;

#define DEVFN __device__ __forceinline__

DEVFN float blockReduceSum(float v, float* buf) {
  int t = threadIdx.x;
  buf[t] = v; __syncthreads();
  for (int off = blockDim.x >> 1; off > 0; off >>= 1) {
    if (t < off) buf[t] += buf[t + off];
    __syncthreads();
  }
  float r = buf[0];
  __syncthreads();
  return r;
}

DEVFN float blockReduceMax(float v, float* buf) {
  int t = threadIdx.x;
  buf[t] = v; __syncthreads();
  for (int off = blockDim.x >> 1; off > 0; off >>= 1) {
    if (t < off) buf[t] = fmaxf(buf[t], buf[t + off]);
    __syncthreads();
  }
  float r = buf[0];
  __syncthreads();
  return r;
}

DEVFN float sigmoidf_(float x) { return 1.f / (1.f + __expf(-x)); }

// ---------------- conv 3x3 SAME, NCHW, cross-correlation ----------------
template<int CIN, int COUT, int HW>
__global__ __launch_bounds__(256)
void k_conv3x3(const float* __restrict__ in, const float* __restrict__ w,
               const float* __restrict__ bias, float* __restrict__ outp) {
  constexpr int XQ = HW / 4;
  int idx = blockIdx.x * 256 + threadIdx.x;
  if (idx >= B_ * COUT * HW * XQ) return;
  int xq = idx % XQ;
  int y  = (idx / XQ) % HW;
  int co = (idx / (XQ * HW)) % COUT;
  int b  = idx / (XQ * HW * COUT);
  int x0 = xq * 4;
  float a0, a1, a2, a3;
  a0 = a1 = a2 = a3 = bias[co];
  const float* inb = in + (size_t)b * CIN * HW * HW;
  const float* wc  = w + co * CIN * 9;
  for (int ci = 0; ci < CIN; ++ci) {
    const float* ip = inb + ci * HW * HW;
    const float* wp = wc + ci * 9;
    float w0 = wp[0], w1 = wp[1], w2 = wp[2];
    float w3 = wp[3], w4 = wp[4], w5 = wp[5];
    float w6 = wp[6], w7 = wp[7], w8 = wp[8];
    #pragma unroll
    for (int dy = 0; dy < 3; ++dy) {
      int yy = y + dy - 1;
      if (yy < 0 || yy >= HW) continue;
      const float* row = ip + yy * HW;
      float4 mid = *reinterpret_cast<const float4*>(row + x0);
      float vl = (x0 > 0)       ? row[x0 - 1] : 0.f;
      float vr = (x0 + 4 < HW)  ? row[x0 + 4] : 0.f;
      float u0, u1, u2;
      if (dy == 0)      { u0 = w0; u1 = w1; u2 = w2; }
      else if (dy == 1) { u0 = w3; u1 = w4; u2 = w5; }
      else              { u0 = w6; u1 = w7; u2 = w8; }
      a0 = fmaf(vl,    u0, fmaf(mid.x, u1, fmaf(mid.y, u2, a0)));
      a1 = fmaf(mid.x, u0, fmaf(mid.y, u1, fmaf(mid.z, u2, a1)));
      a2 = fmaf(mid.y, u0, fmaf(mid.z, u1, fmaf(mid.w, u2, a2)));
      a3 = fmaf(mid.z, u0, fmaf(mid.w, u1, fmaf(vr,    u2, a3)));
    }
  }
  float* op = outp + (((size_t)b * COUT + co) * HW + y) * HW + x0;
  *reinterpret_cast<float4*>(op) = make_float4(a0, a1, a2, a3);
}

// ---------------- BatchNorm (train mode) ----------------
template<int C, int HW2>
__global__ __launch_bounds__(256)
void k_bn_stats(const float* __restrict__ x, float* __restrict__ part) {
  int c = blockIdx.x, s = blockIdx.y, ns = gridDim.y;
  const int Npc = B_ * HW2;
  float s1 = 0.f, s2 = 0.f;
  for (int ii = s * 256 + threadIdx.x; ii < Npc; ii += ns * 256) {
    int b = ii / HW2, pos = ii % HW2;
    float v = x[((size_t)b * C + c) * HW2 + pos];
    s1 += v; s2 += v * v;
  }
  __shared__ float r1[256], r2[256];
  r1[threadIdx.x] = s1; r2[threadIdx.x] = s2; __syncthreads();
  for (int off = 128; off > 0; off >>= 1) {
    if (threadIdx.x < off) { r1[threadIdx.x] += r1[threadIdx.x + off]; r2[threadIdx.x] += r2[threadIdx.x + off]; }
    __syncthreads();
  }
  if (threadIdx.x == 0) {
    part[(c * ns + s) * 2 + 0] = r1[0];
    part[(c * ns + s) * 2 + 1] = r2[0];
  }
}

__global__ void k_bn_finalize(const float* __restrict__ part, int C, int ns, float inv_n,
                              const float* __restrict__ g, const float* __restrict__ bb,
                              float2* __restrict__ ss) {
  int c = threadIdx.x;
  if (c >= C) return;
  float s1 = 0.f, s2 = 0.f;
  for (int s = 0; s < ns; ++s) { s1 += part[(c * ns + s) * 2]; s2 += part[(c * ns + s) * 2 + 1]; }
  float m = s1 * inv_n;
  float var = s2 * inv_n - m * m;
  float rstd = rsqrtf(var + 1e-5f);
  float sc = g[c] * rstd;
  ss[c] = make_float2(sc, bb[c] - m * sc);
}

template<int C, int HW2>
__global__ __launch_bounds__(256)
void k_bn_apply_relu(float* __restrict__ x, const float2* __restrict__ ss) {
  int idx = blockIdx.x * 256 + threadIdx.x;
  if (idx >= B_ * C * HW2) return;
  int c = (idx / HW2) % C;
  float2 p = ss[c];
  x[idx] = fmaxf(fmaf(x[idx], p.x, p.y), 0.f);
}

template<int C, int HWIN>
__global__ __launch_bounds__(256)
void k_bn_apply_relu_mp(const float* __restrict__ xin, float* __restrict__ outp,
                        const float2* __restrict__ ss) {
  constexpr int HO = HWIN / 2;
  int idx = blockIdx.x * 256 + threadIdx.x;
  if (idx >= B_ * C * HO * HO) return;
  int xo = idx % HO;
  int yo = (idx / HO) % HO;
  int c  = (idx / (HO * HO)) % C;
  int b  = idx / (HO * HO * C);
  float2 p = ss[c];
  const float* base = xin + ((size_t)(b * C + c) * HWIN + 2 * yo) * HWIN + 2 * xo;
  float m = -INFINITY, v;
  v = fmaxf(fmaf(base[0],        p.x, p.y), 0.f); m = fmaxf(m, v);
  v = fmaxf(fmaf(base[1],        p.x, p.y), 0.f); m = fmaxf(m, v);
  v = fmaxf(fmaf(base[HWIN],     p.x, p.y), 0.f); m = fmaxf(m, v);
  v = fmaxf(fmaf(base[HWIN + 1], p.x, p.y), 0.f); m = fmaxf(m, v);
  outp[idx] = m;
}

// ---------------- adaptive avg pool 16x16 -> 2x2 (8x8 blocks) ----------------
__global__ __launch_bounds__(256)
void k_avgpool(const float* __restrict__ x, float* __restrict__ outp) {
  int idx = blockIdx.x * 256 + threadIdx.x;   // B*256
  if (idx >= B_ * 256) return;
  int b = idx >> 8;
  int r = idx & 255;
  int c = r >> 2, i = (r >> 1) & 1, j = r & 1;
  const float* p = x + ((size_t)(b * 64 + c) * 16 + i * 8) * 16 + j * 8;
  float s = 0.f;
  #pragma unroll
  for (int yy = 0; yy < 8; ++yy)
    #pragma unroll
    for (int xx = 0; xx < 8; ++xx) s += p[yy * 16 + xx];
  outp[idx] = s * (1.f / 64.f);
}

// ---------------- generic small FC (block per row), opt GLU / LN ----------------
template<int K, int NOUT, int R, bool GLU_, bool LN_>
__global__ void k_fc(const float* __restrict__ A, const float* __restrict__ W, int ldw,
                     const float* __restrict__ bias, const float* __restrict__ lng,
                     const float* __restrict__ lnb, float* __restrict__ outp) {
  constexpr int NTHR = NOUT / R;
  int b = blockIdx.x, t = threadIdx.x;
  __shared__ float a[K];
  __shared__ float red[NTHR];
  for (int k = t; k < K; k += NTHR) a[k] = A[b * K + k];
  __syncthreads();
  float res[R];
  #pragma unroll
  for (int r = 0; r < R; ++r) {
    int j = t + r * NTHR;
    float za = bias[j];
    float zb = GLU_ ? bias[j + NOUT] : 0.f;
    for (int k = 0; k < K; ++k) {
      float av = a[k];
      za = fmaf(av, W[(size_t)k * ldw + j], za);
      if (GLU_) zb = fmaf(av, W[(size_t)k * ldw + j + NOUT], zb);
    }
    res[r] = GLU_ ? za * sigmoidf_(zb) : za;
  }
  if (LN_) {
    float s1 = 0.f, s2 = 0.f;
    #pragma unroll
    for (int r = 0; r < R; ++r) { s1 += res[r]; s2 += res[r] * res[r]; }
    s1 = blockReduceSum(s1, red);
    s2 = blockReduceSum(s2, red);
    float mu = s1 / (float)NOUT;
    float rstd = rsqrtf(s2 / (float)NOUT - mu * mu + 1e-5f);
    #pragma unroll
    for (int r = 0; r < R; ++r) {
      int j = t + r * NTHR;
      outp[b * NOUT + j] = fmaf((res[r] - mu) * rstd, lng[j], lnb[j]);
    }
  } else {
    #pragma unroll
    for (int r = 0; r < R; ++r) outp[b * NOUT + t + r * NTHR] = res[r];
  }
}

// ---------------- recurrent state init ----------------
__global__ __launch_bounds__(256)
void k_init(const float* __restrict__ sa, const float* __restrict__ st,
            const int* __restrict__ oL, const int* __restrict__ oR,
            float* __restrict__ act, float* __restrict__ trace,
            float* __restrict__ ao, float* __restrict__ bo) {
  int idx = blockIdx.x * 256 + threadIdx.x;
  if (idx < B_ * N_ * M_) trace[idx] = st[idx % (N_ * M_)];
  if (idx < B_ * N_)      act[idx]   = sa[idx % N_];
  if (idx < B_ * NSO_) {
    int i = idx % NSO_;
    ao[idx] = sa[oL[i]] * sa[oR[i]];
    bo[idx] = 1.f;
  }
}

// ---------------- per-tick: syn GEMM + GLU ----------------
// z[b][i]      = synconst[b][i]      + sum_k act[b][k]*synw[512+k][i]
// z[b][1024+i] = synconst[b][1024+i] + sum_k act[b][k]*synw[512+k][1024+i]
// sraw[b][i]   = z_a * sigmoid(z_b)
__global__ __launch_bounds__(256)
void k_syn_glu(const float* __restrict__ act, const float* __restrict__ synw,
               const float* __restrict__ synconst, float* __restrict__ sraw) {
  int bg = blockIdx.x & 15;     // group of 4 batch rows
  int ig = blockIdx.x >> 4;     // chunk of 64 i
  int bsub = threadIdx.x >> 6;
  int isub = threadIdx.x & 63;
  int b = bg * 4 + bsub;
  int i = ig * 64 + isub;
  __shared__ float a[4][1024];
  for (int k = threadIdx.x; k < 4096; k += 256)
    a[k >> 10][k & 1023] = act[(size_t)(bg * 4 + (k >> 10)) * 1024 + (k & 1023)];
  __syncthreads();
  const float* wpa = synw + (size_t)512 * 2048 + i;
  const float* wpb = wpa + 1024;
  float za = synconst[b * 2048 + i];
  float zb = synconst[b * 2048 + 1024 + i];
  const float* ar = a[bsub];
  #pragma unroll 4
  for (int k = 0; k < 1024; ++k) {
    float av = ar[k];
    za = fmaf(av, wpa[(size_t)k * 2048], za);
    zb = fmaf(av, wpb[(size_t)k * 2048], zb);
  }
  sraw[b * 1024 + i] = za * sigmoidf_(zb);
}

// ---------------- per-tick: LN + append to trace ring (slot) ----------------
__global__ __launch_bounds__(256)
void k_ln_trace(const float* __restrict__ sraw, const float* __restrict__ g,
                const float* __restrict__ bb, float* __restrict__ trace, int slot) {
  int b = blockIdx.x, t = threadIdx.x;
  __shared__ float red[256];
  float v[4]; float s1 = 0.f, s2 = 0.f;
  #pragma unroll
  for (int r = 0; r < 4; ++r) {
    v[r] = sraw[b * 1024 + t + r * 256];
    s1 += v[r]; s2 += v[r] * v[r];
  }
  s1 = blockReduceSum(s1, red);
  s2 = blockReduceSum(s2, red);
  float mu = s1 * (1.f / 1024.f);
  float rstd = rsqrtf(s2 * (1.f / 1024.f) - mu * mu + 1e-5f);
  #pragma unroll
  for (int r = 0; r < 4; ++r) {
    int n = t + r * 256;
    trace[((size_t)b * N_ + n) * M_ + slot] = fmaf((v[r] - mu) * rstd, g[n], bb[n]);
  }
}

// ---------------- per-tick: per-neuron private MLP ----------------
// block = one neuron n, 128 threads (thread t = GLU output column t)
// ring: physical slot p holds logical m where p=(m+tick+1)&31  =>  m=(p-tick-1)&31
__global__ __launch_bounds__(128)
void k_nlm(const float* __restrict__ trace, const float* __restrict__ w1,
           const float* __restrict__ b1, const float* __restrict__ w2,
           const float* __restrict__ b2, float* __restrict__ act, int tick) {
  int n = blockIdx.x, t = threadIdx.x;
  __shared__ float tr[64][32];
  __shared__ float hid[128][65];
  __shared__ float comb[64];
  for (int k = t; k < 64 * 32; k += 128) {
    int b = k >> 5, m = k & 31;
    tr[b][m] = trace[((size_t)b * N_ + n) * M_ + m];
  }
  const float* wp = w1 + (size_t)n * (M_ * 256);
  float wa[32], wb[32];
  #pragma unroll
  for (int ms = 0; ms < 32; ++ms) {
    int m = (ms - tick - 1) & 31;
    wa[ms] = wp[m * 256 + t];
    wb[ms] = wp[m * 256 + 128 + t];
  }
  float ba = b1[n * 256 + t];
  float bgt = b1[n * 256 + 128 + t];
  float w2v = w2[n * 128 + t];
  __syncthreads();
  for (int b = 0; b < 64; ++b) {
    const float4* trb = reinterpret_cast<const float4*>(&tr[b][0]);
    float za = ba, zb = bgt;
    #pragma unroll
    for (int q = 0; q < 8; ++q) {
      float4 v = trb[q];
      za = fmaf(v.x, wa[4*q+0], za); zb = fmaf(v.x, wb[4*q+0], zb);
      za = fmaf(v.y, wa[4*q+1], za); zb = fmaf(v.y, wb[4*q+1], zb);
      za = fmaf(v.z, wa[4*q+2], za); zb = fmaf(v.z, wb[4*q+2], zb);
      za = fmaf(v.w, wa[4*q+3], za); zb = fmaf(v.w, wb[4*q+3], zb);
    }
    hid[t][b] = za * sigmoidf_(zb) * w2v;
  }
  __syncthreads();
  int bb2 = t & 63, half = t >> 6;
  float s = 0.f;
  #pragma unroll 8
  for (int q = 0; q < 64; ++q) s += hid[half * 64 + q][bb2];
  if (half == 1) comb[bb2] = s;
  __syncthreads();
  if (half == 0) act[(size_t)bb2 * N_ + n] = s + comb[bb2] + b2[n];
}

// ---------------- per-tick: sync_o + output MLP + pred + cert ----------------
__global__ __launch_bounds__(256)
void k_outpath(const float* __restrict__ act, float* __restrict__ ao, float* __restrict__ bo,
               const float* __restrict__ dec_o, const int* __restrict__ oL, const int* __restrict__ oR,
               const float* __restrict__ opw1, const float* __restrict__ opb1,
               const float* __restrict__ l1g, const float* __restrict__ l1b,
               const float* __restrict__ opw2, const float* __restrict__ opb2,
               const float* __restrict__ l2g, const float* __restrict__ l2b,
               const float* __restrict__ opw3, const float* __restrict__ opb3,
               float* __restrict__ outp, int tick) {
  int b = blockIdx.x, t = threadIdx.x;
  __shared__ float red[256];
  __shared__ float syo[256], h1s[256], h2s[64];
  const float* actb = act + (size_t)b * 1024;
  float po = actb[oL[t]] * actb[oR[t]];
  float r = __expf(-fminf(fmaxf(dec_o[t], 0.f), 15.f));
  int ai = b * 256 + t;
  float av = fmaf(r, ao[ai], po);
  float bv = fmaf(r, bo[ai], 1.f);
  ao[ai] = av; bo[ai] = bv;
  syo[t] = av * rsqrtf(bv + 1e-8f);
  __syncthreads();
  // h1 = relu(LN(syo @ opw1 + opb1))
  float z = opb1[t];
  for (int k = 0; k < 256; ++k) z = fmaf(syo[k], opw1[k * 256 + t], z);
  float s1 = blockReduceSum(z, red);
  float s2 = blockReduceSum(z * z, red);
  float mu = s1 * (1.f / 256.f);
  float rstd = rsqrtf(s2 * (1.f / 256.f) - mu * mu + 1e-5f);
  h1s[t] = fmaxf(fmaf((z - mu) * rstd, l1g[t], l1b[t]), 0.f);
  __syncthreads();
  // h2 = relu(LN(h1 @ opw2 + opb2)) : 64 outputs, wave 0
  if (t < 64) {
    float z2 = opb2[t];
    for (int k = 0; k < 256; ++k) z2 = fmaf(h1s[k], opw2[k * 64 + t], z2);
    float a1 = z2, a2 = z2 * z2;
    #pragma unroll
    for (int o = 32; o > 0; o >>= 1) { a1 += __shfl_xor(a1, o); a2 += __shfl_xor(a2, o); }
    float mu2 = a1 * (1.f / 64.f);
    float rs2 = rsqrtf(a2 * (1.f / 64.f) - mu2 * mu2 + 1e-5f);
    h2s[t] = fmaxf(fmaf((z2 - mu2) * rs2, l2g[t], l2b[t]), 0.f);
  }
  __syncthreads();
  // pred = h2 @ opw3 + opb3 ; softmax entropy -> cert
  float zp[4];
  float mymax = -INFINITY;
  #pragma unroll
  for (int g2 = 0; g2 < 4; ++g2) {
    int j = t + g2 * 256;
    if (j < OUT_) {
      float z3 = opb3[j];
      for (int k = 0; k < 64; ++k) z3 = fmaf(h2s[k], opw3[k * OUT_ + j], z3);
      outp[(size_t)b * (OUT_ * T_) + (size_t)j * T_ + tick] = z3;
      zp[g2] = z3;
      mymax = fmaxf(mymax, z3);
    } else zp[g2] = -INFINITY;
  }
  float mx = blockReduceMax(mymax, red);
  float es = 0.f;
  #pragma unroll
  for (int g2 = 0; g2 < 4; ++g2) {
    if (t + g2 * 256 < OUT_) { zp[g2] = __expf(zp[g2] - mx); es += zp[g2]; }
    else zp[g2] = 0.f;
  }
  float S = blockReduceSum(es, red);
  float inv = 1.f / S;
  float ep = 0.f;
  #pragma unroll
  for (int g2 = 0; g2 < 4; ++g2) {
    if (t + g2 * 256 < OUT_) {
      float p = zp[g2] * inv;
      ep += p * __logf(p + 1e-10f);
    }
  }
  float ent = -blockReduceSum(ep, red);
  if (t == 0) {
    float ne = ent * (1.f / logf(1000.f));
    outp[(size_t)B_ * OUT_ * T_ + (size_t)b * 2 * T_ + tick]      = ne;
    outp[(size_t)B_ * OUT_ * T_ + (size_t)b * 2 * T_ + T_ + tick] = 1.f - ne;
  }
}

extern "C" void kernel_launch(void* const* d_in, const int* in_sizes, int n_in,
                              void* d_out, int out_size, void* d_ws, size_t ws_size,
                              hipStream_t stream) {
  (void)in_sizes; (void)n_in; (void)out_size; (void)ws_size;
  const float* x      = (const float*)d_in[0];
  const float* c1w    = (const float*)d_in[1];
  const float* c1b    = (const float*)d_in[2];
  const float* bn1g   = (const float*)d_in[3];
  const float* bn1b   = (const float*)d_in[4];
  const float* c2w    = (const float*)d_in[5];
  const float* c2b    = (const float*)d_in[6];
  const float* bn2g   = (const float*)d_in[7];
  const float* bn2b   = (const float*)d_in[8];
  const float* c3w    = (const float*)d_in[9];
  const float* c3b    = (const float*)d_in[10];
  const float* bn3g   = (const float*)d_in[11];
  const float* bn3b   = (const float*)d_in[12];
  const float* c4w    = (const float*)d_in[13];
  const float* c4b    = (const float*)d_in[14];
  const float* bn4g   = (const float*)d_in[15];
  const float* bn4b   = (const float*)d_in[16];
  const float* fc1w   = (const float*)d_in[17];
  const float* fc1b   = (const float*)d_in[18];
  const float* fc2w   = (const float*)d_in[19];
  const float* fc2b   = (const float*)d_in[20];
  const float* kvw    = (const float*)d_in[21];
  const float* kvb    = (const float*)d_in[22];
  const float* kvlg   = (const float*)d_in[23];
  const float* kvlb   = (const float*)d_in[24];
  const float* synw   = (const float*)d_in[25];
  const float* synb   = (const float*)d_in[26];
  const float* synlg  = (const float*)d_in[27];
  const float* synlb  = (const float*)d_in[28];
  const float* nlmw1  = (const float*)d_in[29];
  const float* nlmb1  = (const float*)d_in[30];
  const float* nlmw2  = (const float*)d_in[31];
  const float* nlmb2  = (const float*)d_in[32];
  const float* sact   = (const float*)d_in[33];
  const float* strc   = (const float*)d_in[34];
  const float* dec_o  = (const float*)d_in[36];
  const float* attn_inw = (const float*)d_in[39];
  const float* attn_inb = (const float*)d_in[40];
  const float* attn_ow  = (const float*)d_in[41];
  const float* attn_ob  = (const float*)d_in[42];
  const float* opw1   = (const float*)d_in[43];
  const float* opb1   = (const float*)d_in[44];
  const float* opl1g  = (const float*)d_in[45];
  const float* opl1b  = (const float*)d_in[46];
  const float* opw2   = (const float*)d_in[47];
  const float* opb2   = (const float*)d_in[48];
  const float* opl2g  = (const float*)d_in[49];
  const float* opl2b  = (const float*)d_in[50];
  const float* opw3   = (const float*)d_in[51];
  const float* opb3   = (const float*)d_in[52];
  const int*   oL     = (const int*)d_in[55];
  const int*   oR     = (const int*)d_in[56];
  float* outp = (float*)d_out;
  float* ws   = (float*)d_ws;

  // workspace layout (floats); total ~14.69M floats = 58.8 MB
  float* c2buf = ws;                   // 8,388,608  (conv2 out; later conv4 out)
  float* c1buf = ws + 8388608;         // 4,194,304  (conv1 out; later conv3 out)
  float* trace = ws + 8388608;         // 2,097,152  (reuses c1buf after encoder)
  float* act   = ws + 10485760;        // 65,536
  float* sraw  = ws + 10551296;        // 65,536
  float* syncst= ws + 10616832;        // 131,072
  float* pooled= ws + 10747904;        // 16,384
  float* ench  = ws + 10764288;        // 8,192
  float* enc   = ws + 10772480;        // 32,768
  float* kvbuf = ws + 10805248;        // 32,768
  float* vhbuf = ws + 10838016;        // 32,768
  float* aout  = ws + 10870784;        // 32,768
  float* ao    = ws + 10903552;        // 16,384
  float* bo    = ws + 10919936;        // 16,384
  float* c2p   = ws + 12582912;        // 2,097,152  (conv2 pooled; later conv3 pooled)
  float* bnpart= ws + 14680064;        // 4,096
  float2* bnss = (float2*)(ws + 14684160); // 64 float2

  // ---- encoder ----
  k_conv3x3<3,16,64><<<4096,256,0,stream>>>(x, c1w, c1b, c1buf);
  k_bn_stats<16,4096><<<dim3(16,32),256,0,stream>>>(c1buf, bnpart);
  k_bn_finalize<<<1,64,0,stream>>>(bnpart, 16, 32, 1.f/(float)(B_*4096), bn1g, bn1b, bnss);
  k_bn_apply_relu<16,4096><<<16384,256,0,stream>>>(c1buf, bnss);

  k_conv3x3<16,32,64><<<8192,256,0,stream>>>(c1buf, c2w, c2b, c2buf);
  k_bn_stats<32,4096><<<dim3(32,32),256,0,stream>>>(c2buf, bnpart);
  k_bn_finalize<<<1,64,0,stream>>>(bnpart, 32, 32, 1.f/(float)(B_*4096), bn2g, bn2b, bnss);
  k_bn_apply_relu_mp<32,64><<<8192,256,0,stream>>>(c2buf, c2p, bnss);

  k_conv3x3<32,64,32><<<4096,256,0,stream>>>(c2p, c3w, c3b, c1buf);
  k_bn_stats<64,1024><<<dim3(64,16),256,0,stream>>>(c1buf, bnpart);
  k_bn_finalize<<<1,64,0,stream>>>(bnpart, 64, 16, 1.f/(float)(B_*1024), bn3g, bn3b, bnss);
  k_bn_apply_relu_mp<64,32><<<4096,256,0,stream>>>(c1buf, c2p, bnss);

  k_conv3x3<64,64,16><<<1024,256,0,stream>>>(c2p, c4w, c4b, c2buf);
  k_bn_stats<64,256><<<dim3(64,8),256,0,stream>>>(c2buf, bnpart);
  k_bn_finalize<<<1,64,0,stream>>>(bnpart, 64, 8, 1.f/(float)(B_*256), bn4g, bn4b, bnss);
  k_bn_apply_relu<64,256><<<4096,256,0,stream>>>(c2buf, bnss);

  k_avgpool<<<64,256,0,stream>>>(c2buf, pooled);
  k_fc<256,128,1,true,false><<<64,128,0,stream>>>(pooled, fc1w, 256, fc1b, nullptr, nullptr, ench);
  k_fc<128,512,2,false,false><<<64,256,0,stream>>>(ench, fc2w, 512, fc2b, nullptr, nullptr, enc);
  k_fc<512,512,2,false,true><<<64,256,0,stream>>>(enc, kvw, 512, kvb, kvlg, kvlb, kvbuf);
  // vh = kv @ Wv + bv   (Wv = attn_inw[:,1024:1536])   [attention weights are identically 1 -> q,k dead]
  k_fc<512,512,2,false,false><<<64,256,0,stream>>>(kvbuf, attn_inw + 1024, 1536, attn_inb + 1024, nullptr, nullptr, vhbuf);
  // attn_out = vh @ attn_ow + attn_ob   (tick-invariant)
  k_fc<512,512,2,false,false><<<64,256,0,stream>>>(vhbuf, attn_ow, 512, attn_ob, nullptr, nullptr, aout);
  // synconst = attn_out @ synw[0:512] + synb
  k_fc<512,2048,8,false,false><<<64,256,0,stream>>>(aout, synw, 2048, synb, nullptr, nullptr, syncst);

  k_init<<<8192,256,0,stream>>>(sact, strc, oL, oR, act, trace, ao, bo);

  // ---- recurrent ticks ----
  for (int t = 0; t < T_; ++t) {
    k_syn_glu<<<256,256,0,stream>>>(act, synw, syncst, sraw);
    k_ln_trace<<<64,256,0,stream>>>(sraw, synlg, synlb, trace, t);
    k_nlm<<<1024,128,0,stream>>>(trace, nlmw1, nlmb1, nlmw2, nlmb2, act, t);
    k_outpath<<<64,256,0,stream>>>(act, ao, bo, dec_o, oL, oR,
                                   opw1, opb1, opl1g, opl1b,
                                   opw2, opb2, opl2g, opl2b,
                                   opw3, opb3, outp, t);
  }
}

// Round 2
// 1526.489 us; speedup vs baseline: 1.7808x; 1.7808x over previous
//
#include <hip/hip_runtime.h>
#include <math.h>

// Problem constants
constexpr int B_ = 64, N_ = 1024, M_ = 32, T_ = 8;
constexpr int OUT_ = 1000, NSO_ = 256;

#define DEVFN __device__ __forceinline__

DEVFN float blockReduceSum(float v, float* buf) {
  int t = threadIdx.x;
  buf[t] = v; __syncthreads();
  for (int off = blockDim.x >> 1; off > 0; off >>= 1) {
    if (t < off) buf[t] += buf[t + off];
    __syncthreads();
  }
  float r = buf[0];
  __syncthreads();
  return r;
}

DEVFN float blockReduceMax(float v, float* buf) {
  int t = threadIdx.x;
  buf[t] = v; __syncthreads();
  for (int off = blockDim.x >> 1; off > 0; off >>= 1) {
    if (t < off) buf[t] = fmaxf(buf[t], buf[t + off]);
    __syncthreads();
  }
  float r = buf[0];
  __syncthreads();
  return r;
}

DEVFN float sigmoidf_(float x) { return 1.f / (1.f + __expf(-x)); }

// ---------------- conv 3x3 SAME, NCHW, cross-correlation ----------------
template<int CIN, int COUT, int HW>
__global__ __launch_bounds__(256)
void k_conv3x3(const float* __restrict__ in, const float* __restrict__ w,
               const float* __restrict__ bias, float* __restrict__ outp) {
  constexpr int XQ = HW / 4;
  int idx = blockIdx.x * 256 + threadIdx.x;
  if (idx >= B_ * COUT * HW * XQ) return;
  int xq = idx % XQ;
  int y  = (idx / XQ) % HW;
  int co = (idx / (XQ * HW)) % COUT;
  int b  = idx / (XQ * HW * COUT);
  int x0 = xq * 4;
  float a0, a1, a2, a3;
  a0 = a1 = a2 = a3 = bias[co];
  const float* inb = in + (size_t)b * CIN * HW * HW;
  const float* wc  = w + co * CIN * 9;
  for (int ci = 0; ci < CIN; ++ci) {
    const float* ip = inb + ci * HW * HW;
    const float* wp = wc + ci * 9;
    float w0 = wp[0], w1 = wp[1], w2 = wp[2];
    float w3 = wp[3], w4 = wp[4], w5 = wp[5];
    float w6 = wp[6], w7 = wp[7], w8 = wp[8];
    #pragma unroll
    for (int dy = 0; dy < 3; ++dy) {
      int yy = y + dy - 1;
      if (yy < 0 || yy >= HW) continue;
      const float* row = ip + yy * HW;
      float4 mid = *reinterpret_cast<const float4*>(row + x0);
      float vl = (x0 > 0)       ? row[x0 - 1] : 0.f;
      float vr = (x0 + 4 < HW)  ? row[x0 + 4] : 0.f;
      float u0, u1, u2;
      if (dy == 0)      { u0 = w0; u1 = w1; u2 = w2; }
      else if (dy == 1) { u0 = w3; u1 = w4; u2 = w5; }
      else              { u0 = w6; u1 = w7; u2 = w8; }
      a0 = fmaf(vl,    u0, fmaf(mid.x, u1, fmaf(mid.y, u2, a0)));
      a1 = fmaf(mid.x, u0, fmaf(mid.y, u1, fmaf(mid.z, u2, a1)));
      a2 = fmaf(mid.y, u0, fmaf(mid.z, u1, fmaf(mid.w, u2, a2)));
      a3 = fmaf(mid.z, u0, fmaf(mid.w, u1, fmaf(vr,    u2, a3)));
    }
  }
  float* op = outp + (((size_t)b * COUT + co) * HW + y) * HW + x0;
  *reinterpret_cast<float4*>(op) = make_float4(a0, a1, a2, a3);
}

// ---------------- BatchNorm (train mode) ----------------
template<int C, int HW2>
__global__ __launch_bounds__(256)
void k_bn_stats(const float* __restrict__ x, float* __restrict__ part) {
  int c = blockIdx.x, s = blockIdx.y, ns = gridDim.y;
  const int Npc = B_ * HW2;
  float s1 = 0.f, s2 = 0.f;
  for (int ii = s * 256 + threadIdx.x; ii < Npc; ii += ns * 256) {
    int b = ii / HW2, pos = ii % HW2;
    float v = x[((size_t)b * C + c) * HW2 + pos];
    s1 += v; s2 += v * v;
  }
  __shared__ float r1[256], r2[256];
  r1[threadIdx.x] = s1; r2[threadIdx.x] = s2; __syncthreads();
  for (int off = 128; off > 0; off >>= 1) {
    if (threadIdx.x < off) { r1[threadIdx.x] += r1[threadIdx.x + off]; r2[threadIdx.x] += r2[threadIdx.x + off]; }
    __syncthreads();
  }
  if (threadIdx.x == 0) {
    part[(c * ns + s) * 2 + 0] = r1[0];
    part[(c * ns + s) * 2 + 1] = r2[0];
  }
}

__global__ void k_bn_finalize(const float* __restrict__ part, int C, int ns, float inv_n,
                              const float* __restrict__ g, const float* __restrict__ bb,
                              float2* __restrict__ ss) {
  int c = threadIdx.x;
  if (c >= C) return;
  float s1 = 0.f, s2 = 0.f;
  for (int s = 0; s < ns; ++s) { s1 += part[(c * ns + s) * 2]; s2 += part[(c * ns + s) * 2 + 1]; }
  float m = s1 * inv_n;
  float var = s2 * inv_n - m * m;
  float rstd = rsqrtf(var + 1e-5f);
  float sc = g[c] * rstd;
  ss[c] = make_float2(sc, bb[c] - m * sc);
}

template<int C, int HW2>
__global__ __launch_bounds__(256)
void k_bn_apply_relu(float* __restrict__ x, const float2* __restrict__ ss) {
  int idx = blockIdx.x * 256 + threadIdx.x;
  if (idx >= B_ * C * HW2) return;
  int c = (idx / HW2) % C;
  float2 p = ss[c];
  x[idx] = fmaxf(fmaf(x[idx], p.x, p.y), 0.f);
}

template<int C, int HWIN>
__global__ __launch_bounds__(256)
void k_bn_apply_relu_mp(const float* __restrict__ xin, float* __restrict__ outp,
                        const float2* __restrict__ ss) {
  constexpr int HO = HWIN / 2;
  int idx = blockIdx.x * 256 + threadIdx.x;
  if (idx >= B_ * C * HO * HO) return;
  int xo = idx % HO;
  int yo = (idx / HO) % HO;
  int c  = (idx / (HO * HO)) % C;
  int b  = idx / (HO * HO * C);
  float2 p = ss[c];
  const float* base = xin + ((size_t)(b * C + c) * HWIN + 2 * yo) * HWIN + 2 * xo;
  float m = -INFINITY, v;
  v = fmaxf(fmaf(base[0],        p.x, p.y), 0.f); m = fmaxf(m, v);
  v = fmaxf(fmaf(base[1],        p.x, p.y), 0.f); m = fmaxf(m, v);
  v = fmaxf(fmaf(base[HWIN],     p.x, p.y), 0.f); m = fmaxf(m, v);
  v = fmaxf(fmaf(base[HWIN + 1], p.x, p.y), 0.f); m = fmaxf(m, v);
  outp[idx] = m;
}

// ---------------- adaptive avg pool 16x16 -> 2x2 (8x8 blocks) ----------------
__global__ __launch_bounds__(256)
void k_avgpool(const float* __restrict__ x, float* __restrict__ outp) {
  int idx = blockIdx.x * 256 + threadIdx.x;   // B*256
  if (idx >= B_ * 256) return;
  int b = idx >> 8;
  int r = idx & 255;
  int c = r >> 2, i = (r >> 1) & 1, j = r & 1;
  const float* p = x + ((size_t)(b * 64 + c) * 16 + i * 8) * 16 + j * 8;
  float s = 0.f;
  #pragma unroll
  for (int yy = 0; yy < 8; ++yy)
    #pragma unroll
    for (int xx = 0; xx < 8; ++xx) s += p[yy * 16 + xx];
  outp[idx] = s * (1.f / 64.f);
}

// ---------------- split-K GEMM: A(64 x K) @ W(K x NOUT) -> partials ----------------
// grid: (NOUT/32, K/64); block 256. part[ks][b][j] = sum over k-chunk.
template<int K, int NOUT>
__global__ __launch_bounds__(256)
void k_gemm_part(const float* __restrict__ A, const float* __restrict__ W, int ldw,
                 float* __restrict__ part) {
  int jt = blockIdx.x, ks = blockIdx.y;
  int k0 = ks * 64;
  __shared__ float As[64][65];
  for (int i = threadIdx.x; i < 4096; i += 256) {
    int r = i >> 6, c = i & 63;
    As[r][c] = A[(size_t)r * K + k0 + c];
  }
  __syncthreads();
  int jsub = threadIdx.x & 31;
  int bg = threadIdx.x >> 5;    // 0..7, 8 rows each
  int j = jt * 32 + jsub;
  float acc[8] = {0.f, 0.f, 0.f, 0.f, 0.f, 0.f, 0.f, 0.f};
  const float* wp = W + (size_t)k0 * ldw + j;
  #pragma unroll 8
  for (int kk = 0; kk < 64; ++kk) {
    float w = wp[(size_t)kk * ldw];
    #pragma unroll
    for (int r = 0; r < 8; ++r) acc[r] = fmaf(As[bg * 8 + r][kk], w, acc[r]);
  }
  float* pp = part + (size_t)ks * 64 * NOUT + j;
  #pragma unroll
  for (int r = 0; r < 8; ++r) pp[(size_t)(bg * 8 + r) * NOUT] = acc[r];
}

// ---------------- reduce partials + bias (+GLU) (+LN) ----------------
// block per batch row b, 256 threads. bias indexed bias[b*bstride + j] (bstride=0 for
// shared bias, =NOUT for per-row constant like synconst).
template<int NOUT, int NO_FIN, int KS, bool GLU_, bool LN_>
__global__ __launch_bounds__(256)
void k_fc_reduce(const float* __restrict__ part, const float* __restrict__ bias, int bstride,
                 const float* __restrict__ lng, const float* __restrict__ lnb,
                 float* __restrict__ outp) {
  constexpr int R = (NO_FIN + 255) / 256;
  int b = blockIdx.x, t = threadIdx.x;
  const float* bp = bias + (size_t)b * bstride;
  float v[R];
  #pragma unroll
  for (int r = 0; r < R; ++r) {
    int j = t + r * 256;
    if (j < NO_FIN) {
      float za = bp[j];
      float zb = GLU_ ? bp[j + NO_FIN] : 0.f;
      #pragma unroll
      for (int ks = 0; ks < KS; ++ks) {
        const float* pr = part + ((size_t)ks * 64 + b) * NOUT;
        za += pr[j];
        if (GLU_) zb += pr[j + NO_FIN];
      }
      v[r] = GLU_ ? za * sigmoidf_(zb) : za;
    } else v[r] = 0.f;
  }
  if (LN_) {
    __shared__ float red[256];
    float s1 = 0.f, s2 = 0.f;
    #pragma unroll
    for (int r = 0; r < R; ++r) { s1 += v[r]; s2 += v[r] * v[r]; }
    s1 = blockReduceSum(s1, red);
    s2 = blockReduceSum(s2, red);
    float mu = s1 / (float)NO_FIN;
    float rstd = rsqrtf(s2 / (float)NO_FIN - mu * mu + 1e-5f);
    #pragma unroll
    for (int r = 0; r < R; ++r) {
      int j = t + r * 256;
      if (j < NO_FIN) outp[(size_t)b * NO_FIN + j] = fmaf((v[r] - mu) * rstd, lng[j], lnb[j]);
    }
  } else {
    #pragma unroll
    for (int r = 0; r < R; ++r) {
      int j = t + r * 256;
      if (j < NO_FIN) outp[(size_t)b * NO_FIN + j] = v[r];
    }
  }
}

// ---------------- recurrent state init ----------------
__global__ __launch_bounds__(256)
void k_init(const float* __restrict__ sa, const float* __restrict__ st,
            const int* __restrict__ oL, const int* __restrict__ oR,
            float* __restrict__ act, float* __restrict__ trace,
            float* __restrict__ ao, float* __restrict__ bo) {
  int idx = blockIdx.x * 256 + threadIdx.x;
  if (idx < B_ * N_ * M_) trace[idx] = st[idx % (N_ * M_)];
  if (idx < B_ * N_)      act[idx]   = sa[idx % N_];
  if (idx < B_ * NSO_) {
    int i = idx % NSO_;
    ao[idx] = sa[oL[i]] * sa[oR[i]];
    bo[idx] = 1.f;
  }
}

// ---------------- per-tick: LN + append to trace ring (slot) ----------------
__global__ __launch_bounds__(256)
void k_ln_trace(const float* __restrict__ sraw, const float* __restrict__ g,
                const float* __restrict__ bb, float* __restrict__ trace, int slot) {
  int b = blockIdx.x, t = threadIdx.x;
  __shared__ float red[256];
  float v[4]; float s1 = 0.f, s2 = 0.f;
  #pragma unroll
  for (int r = 0; r < 4; ++r) {
    v[r] = sraw[b * 1024 + t + r * 256];
    s1 += v[r]; s2 += v[r] * v[r];
  }
  s1 = blockReduceSum(s1, red);
  s2 = blockReduceSum(s2, red);
  float mu = s1 * (1.f / 1024.f);
  float rstd = rsqrtf(s2 * (1.f / 1024.f) - mu * mu + 1e-5f);
  #pragma unroll
  for (int r = 0; r < 4; ++r) {
    int n = t + r * 256;
    trace[((size_t)b * N_ + n) * M_ + slot] = fmaf((v[r] - mu) * rstd, g[n], bb[n]);
  }
}

// ---------------- per-tick: per-neuron private MLP ----------------
// block = one neuron n, 128 threads (thread t = GLU output column t)
// ring: physical slot p holds logical m where p=(m+tick+1)&31  =>  m=(p-tick-1)&31
__global__ __launch_bounds__(128)
void k_nlm(const float* __restrict__ trace, const float* __restrict__ w1,
           const float* __restrict__ b1, const float* __restrict__ w2,
           const float* __restrict__ b2, float* __restrict__ act, int tick) {
  int n = blockIdx.x, t = threadIdx.x;
  __shared__ float tr[64][32];
  __shared__ float hid[128][65];
  __shared__ float comb[64];
  for (int k = t; k < 64 * 32; k += 128) {
    int b = k >> 5, m = k & 31;
    tr[b][m] = trace[((size_t)b * N_ + n) * M_ + m];
  }
  const float* wp = w1 + (size_t)n * (M_ * 256);
  float wa[32], wb[32];
  #pragma unroll
  for (int ms = 0; ms < 32; ++ms) {
    int m = (ms - tick - 1) & 31;
    wa[ms] = wp[m * 256 + t];
    wb[ms] = wp[m * 256 + 128 + t];
  }
  float ba = b1[n * 256 + t];
  float bgt = b1[n * 256 + 128 + t];
  float w2v = w2[n * 128 + t];
  __syncthreads();
  for (int b = 0; b < 64; ++b) {
    const float4* trb = reinterpret_cast<const float4*>(&tr[b][0]);
    float za = ba, zb = bgt;
    #pragma unroll
    for (int q = 0; q < 8; ++q) {
      float4 v = trb[q];
      za = fmaf(v.x, wa[4*q+0], za); zb = fmaf(v.x, wb[4*q+0], zb);
      za = fmaf(v.y, wa[4*q+1], za); zb = fmaf(v.y, wb[4*q+1], zb);
      za = fmaf(v.z, wa[4*q+2], za); zb = fmaf(v.z, wb[4*q+2], zb);
      za = fmaf(v.w, wa[4*q+3], za); zb = fmaf(v.w, wb[4*q+3], zb);
    }
    hid[t][b] = za * sigmoidf_(zb) * w2v;
  }
  __syncthreads();
  int bb2 = t & 63, half = t >> 6;
  float s = 0.f;
  #pragma unroll 8
  for (int q = 0; q < 64; ++q) s += hid[half * 64 + q][bb2];
  if (half == 1) comb[bb2] = s;
  __syncthreads();
  if (half == 0) act[(size_t)bb2 * N_ + n] = s + comb[bb2] + b2[n];
}

// ---------------- per-tick: sync_o + output MLP + pred + cert ----------------
__global__ __launch_bounds__(256)
void k_outpath(const float* __restrict__ act, float* __restrict__ ao, float* __restrict__ bo,
               const float* __restrict__ dec_o, const int* __restrict__ oL, const int* __restrict__ oR,
               const float* __restrict__ opw1, const float* __restrict__ opb1,
               const float* __restrict__ l1g, const float* __restrict__ l1b,
               const float* __restrict__ opw2, const float* __restrict__ opb2,
               const float* __restrict__ l2g, const float* __restrict__ l2b,
               const float* __restrict__ opw3, const float* __restrict__ opb3,
               float* __restrict__ outp, int tick) {
  int b = blockIdx.x, t = threadIdx.x;
  __shared__ float red[256];
  __shared__ float syo[256], h1s[256], h2s[64];
  const float* actb = act + (size_t)b * 1024;
  float po = actb[oL[t]] * actb[oR[t]];
  float r = __expf(-fminf(fmaxf(dec_o[t], 0.f), 15.f));
  int ai = b * 256 + t;
  float av = fmaf(r, ao[ai], po);
  float bv = fmaf(r, bo[ai], 1.f);
  ao[ai] = av; bo[ai] = bv;
  syo[t] = av * rsqrtf(bv + 1e-8f);
  __syncthreads();
  // h1 = relu(LN(syo @ opw1 + opb1))
  float z = opb1[t];
  for (int k = 0; k < 256; ++k) z = fmaf(syo[k], opw1[k * 256 + t], z);
  float s1 = blockReduceSum(z, red);
  float s2 = blockReduceSum(z * z, red);
  float mu = s1 * (1.f / 256.f);
  float rstd = rsqrtf(s2 * (1.f / 256.f) - mu * mu + 1e-5f);
  h1s[t] = fmaxf(fmaf((z - mu) * rstd, l1g[t], l1b[t]), 0.f);
  __syncthreads();
  // h2 = relu(LN(h1 @ opw2 + opb2)) : 64 outputs, wave 0
  if (t < 64) {
    float z2 = opb2[t];
    for (int k = 0; k < 256; ++k) z2 = fmaf(h1s[k], opw2[k * 64 + t], z2);
    float a1 = z2, a2 = z2 * z2;
    #pragma unroll
    for (int o = 32; o > 0; o >>= 1) { a1 += __shfl_xor(a1, o); a2 += __shfl_xor(a2, o); }
    float mu2 = a1 * (1.f / 64.f);
    float rs2 = rsqrtf(a2 * (1.f / 64.f) - mu2 * mu2 + 1e-5f);
    h2s[t] = fmaxf(fmaf((z2 - mu2) * rs2, l2g[t], l2b[t]), 0.f);
  }
  __syncthreads();
  // pred = h2 @ opw3 + opb3 ; softmax entropy -> cert
  float zp[4];
  float mymax = -INFINITY;
  #pragma unroll
  for (int g2 = 0; g2 < 4; ++g2) {
    int j = t + g2 * 256;
    if (j < OUT_) {
      float z3 = opb3[j];
      for (int k = 0; k < 64; ++k) z3 = fmaf(h2s[k], opw3[k * OUT_ + j], z3);
      outp[(size_t)b * (OUT_ * T_) + (size_t)j * T_ + tick] = z3;
      zp[g2] = z3;
      mymax = fmaxf(mymax, z3);
    } else zp[g2] = -INFINITY;
  }
  float mx = blockReduceMax(mymax, red);
  float es = 0.f;
  #pragma unroll
  for (int g2 = 0; g2 < 4; ++g2) {
    if (t + g2 * 256 < OUT_) { zp[g2] = __expf(zp[g2] - mx); es += zp[g2]; }
    else zp[g2] = 0.f;
  }
  float S = blockReduceSum(es, red);
  float inv = 1.f / S;
  float ep = 0.f;
  #pragma unroll
  for (int g2 = 0; g2 < 4; ++g2) {
    if (t + g2 * 256 < OUT_) {
      float p = zp[g2] * inv;
      ep += p * __logf(p + 1e-10f);
    }
  }
  float ent = -blockReduceSum(ep, red);
  if (t == 0) {
    float ne = ent * (1.f / logf(1000.f));
    outp[(size_t)B_ * OUT_ * T_ + (size_t)b * 2 * T_ + tick]      = ne;
    outp[(size_t)B_ * OUT_ * T_ + (size_t)b * 2 * T_ + T_ + tick] = 1.f - ne;
  }
}

extern "C" void kernel_launch(void* const* d_in, const int* in_sizes, int n_in,
                              void* d_out, int out_size, void* d_ws, size_t ws_size,
                              hipStream_t stream) {
  (void)in_sizes; (void)n_in; (void)out_size; (void)ws_size;
  const float* x      = (const float*)d_in[0];
  const float* c1w    = (const float*)d_in[1];
  const float* c1b    = (const float*)d_in[2];
  const float* bn1g   = (const float*)d_in[3];
  const float* bn1b   = (const float*)d_in[4];
  const float* c2w    = (const float*)d_in[5];
  const float* c2b    = (const float*)d_in[6];
  const float* bn2g   = (const float*)d_in[7];
  const float* bn2b   = (const float*)d_in[8];
  const float* c3w    = (const float*)d_in[9];
  const float* c3b    = (const float*)d_in[10];
  const float* bn3g   = (const float*)d_in[11];
  const float* bn3b   = (const float*)d_in[12];
  const float* c4w    = (const float*)d_in[13];
  const float* c4b    = (const float*)d_in[14];
  const float* bn4g   = (const float*)d_in[15];
  const float* bn4b   = (const float*)d_in[16];
  const float* fc1w   = (const float*)d_in[17];
  const float* fc1b   = (const float*)d_in[18];
  const float* fc2w   = (const float*)d_in[19];
  const float* fc2b   = (const float*)d_in[20];
  const float* kvw    = (const float*)d_in[21];
  const float* kvb    = (const float*)d_in[22];
  const float* kvlg   = (const float*)d_in[23];
  const float* kvlb   = (const float*)d_in[24];
  const float* synw   = (const float*)d_in[25];
  const float* synb   = (const float*)d_in[26];
  const float* synlg  = (const float*)d_in[27];
  const float* synlb  = (const float*)d_in[28];
  const float* nlmw1  = (const float*)d_in[29];
  const float* nlmb1  = (const float*)d_in[30];
  const float* nlmw2  = (const float*)d_in[31];
  const float* nlmb2  = (const float*)d_in[32];
  const float* sact   = (const float*)d_in[33];
  const float* strc   = (const float*)d_in[34];
  const float* dec_o  = (const float*)d_in[36];
  const float* attn_inw = (const float*)d_in[39];
  const float* attn_inb = (const float*)d_in[40];
  const float* attn_ow  = (const float*)d_in[41];
  const float* attn_ob  = (const float*)d_in[42];
  const float* opw1   = (const float*)d_in[43];
  const float* opb1   = (const float*)d_in[44];
  const float* opl1g  = (const float*)d_in[45];
  const float* opl1b  = (const float*)d_in[46];
  const float* opw2   = (const float*)d_in[47];
  const float* opb2   = (const float*)d_in[48];
  const float* opl2g  = (const float*)d_in[49];
  const float* opl2b  = (const float*)d_in[50];
  const float* opw3   = (const float*)d_in[51];
  const float* opb3   = (const float*)d_in[52];
  const int*   oL     = (const int*)d_in[55];
  const int*   oR     = (const int*)d_in[56];
  float* outp = (float*)d_out;
  float* ws   = (float*)d_ws;

  // workspace layout (floats); total ~14.69M floats = 58.8 MB
  float* c2buf = ws;                   // 8,388,608  (conv2 out; later conv4 out)
  float* c1buf = ws + 8388608;         // 4,194,304  (conv1 out; later conv3 out)
  float* trace = ws + 8388608;         // 2,097,152  (reuses c1buf after encoder)
  float* act   = ws + 10485760;        // 65,536
  float* sraw  = ws + 10551296;        // 65,536
  float* syncst= ws + 10616832;        // 131,072
  float* pooled= ws + 10747904;        // 16,384
  float* ench  = ws + 10764288;        // 8,192
  float* enc   = ws + 10772480;        // 32,768
  float* kvbuf = ws + 10805248;        // 32,768
  float* vhbuf = ws + 10838016;        // 32,768
  float* aout  = ws + 10870784;        // 32,768
  float* ao    = ws + 10903552;        // 16,384
  float* bo    = ws + 10919936;        // 16,384
  float* c2p   = ws + 12582912;        // 2,097,152  (conv2/3 pooled; later GEMM partials)
  float* part  = c2p;                  // split-K partials (max 16*64*2048 = 2,097,152)
  float* bnpart= ws + 14680064;        // 4,096
  float2* bnss = (float2*)(ws + 14684160); // 64 float2

  // ---- encoder convs ----
  k_conv3x3<3,16,64><<<4096,256,0,stream>>>(x, c1w, c1b, c1buf);
  k_bn_stats<16,4096><<<dim3(16,32),256,0,stream>>>(c1buf, bnpart);
  k_bn_finalize<<<1,64,0,stream>>>(bnpart, 16, 32, 1.f/(float)(B_*4096), bn1g, bn1b, bnss);
  k_bn_apply_relu<16,4096><<<16384,256,0,stream>>>(c1buf, bnss);

  k_conv3x3<16,32,64><<<8192,256,0,stream>>>(c1buf, c2w, c2b, c2buf);
  k_bn_stats<32,4096><<<dim3(32,32),256,0,stream>>>(c2buf, bnpart);
  k_bn_finalize<<<1,64,0,stream>>>(bnpart, 32, 32, 1.f/(float)(B_*4096), bn2g, bn2b, bnss);
  k_bn_apply_relu_mp<32,64><<<8192,256,0,stream>>>(c2buf, c2p, bnss);

  k_conv3x3<32,64,32><<<4096,256,0,stream>>>(c2p, c3w, c3b, c1buf);
  k_bn_stats<64,1024><<<dim3(64,16),256,0,stream>>>(c1buf, bnpart);
  k_bn_finalize<<<1,64,0,stream>>>(bnpart, 64, 16, 1.f/(float)(B_*1024), bn3g, bn3b, bnss);
  k_bn_apply_relu_mp<64,32><<<4096,256,0,stream>>>(c1buf, c2p, bnss);

  k_conv3x3<64,64,16><<<1024,256,0,stream>>>(c2p, c4w, c4b, c2buf);
  k_bn_stats<64,256><<<dim3(64,8),256,0,stream>>>(c2buf, bnpart);
  k_bn_finalize<<<1,64,0,stream>>>(bnpart, 64, 8, 1.f/(float)(B_*256), bn4g, bn4b, bnss);
  k_bn_apply_relu<64,256><<<4096,256,0,stream>>>(c2buf, bnss);

  k_avgpool<<<64,256,0,stream>>>(c2buf, pooled);

  // ---- encoder FC chain (split-K GEMM + fused reduce) ----
  // NOTE: conv work is done; c2p region is free -> reused as `part`.
  // fc1: (64x256)@(256x256) -> GLU -> ench (64x128)
  k_gemm_part<256,256><<<dim3(8,4),256,0,stream>>>(pooled, fc1w, 256, part);
  k_fc_reduce<256,128,4,true,false><<<64,256,0,stream>>>(part, fc1b, 0, nullptr, nullptr, ench);
  // fc2: (64x128)@(128x512) -> enc
  k_gemm_part<128,512><<<dim3(16,2),256,0,stream>>>(ench, fc2w, 512, part);
  k_fc_reduce<512,512,2,false,false><<<64,256,0,stream>>>(part, fc2b, 0, nullptr, nullptr, enc);
  // kv: LN((64x512)@(512x512)) -> kvbuf
  k_gemm_part<512,512><<<dim3(16,8),256,0,stream>>>(enc, kvw, 512, part);
  k_fc_reduce<512,512,8,false,true><<<64,256,0,stream>>>(part, kvb, 0, kvlg, kvlb, kvbuf);
  // vh = kv @ Wv + bv  (Wv = attn_inw[:,1024:1536]; attention weights are identically 1 -> q,k dead)
  k_gemm_part<512,512><<<dim3(16,8),256,0,stream>>>(kvbuf, attn_inw + 1024, 1536, part);
  k_fc_reduce<512,512,8,false,false><<<64,256,0,stream>>>(part, attn_inb + 1024, 0, nullptr, nullptr, vhbuf);
  // attn_out = vh @ attn_ow + attn_ob  (tick-invariant)
  k_gemm_part<512,512><<<dim3(16,8),256,0,stream>>>(vhbuf, attn_ow, 512, part);
  k_fc_reduce<512,512,8,false,false><<<64,256,0,stream>>>(part, attn_ob, 0, nullptr, nullptr, aout);
  // synconst = attn_out @ synw[0:512] + synb  (64x2048)
  k_gemm_part<512,2048><<<dim3(64,8),256,0,stream>>>(aout, synw, 2048, part);
  k_fc_reduce<2048,2048,8,false,false><<<64,256,0,stream>>>(part, synb, 0, nullptr, nullptr, syncst);

  k_init<<<8192,256,0,stream>>>(sact, strc, oL, oR, act, trace, ao, bo);

  // ---- recurrent ticks ----
  for (int t = 0; t < T_; ++t) {
    // syn: z = syncst + act @ synw[512:1536]; sraw = GLU(z)
    k_gemm_part<1024,2048><<<dim3(64,16),256,0,stream>>>(act, synw + (size_t)512 * 2048, 2048, part);
    k_fc_reduce<2048,1024,16,true,false><<<64,256,0,stream>>>(part, syncst, 2048, nullptr, nullptr, sraw);
    k_ln_trace<<<64,256,0,stream>>>(sraw, synlg, synlb, trace, t);
    k_nlm<<<1024,128,0,stream>>>(trace, nlmw1, nlmb1, nlmw2, nlmb2, act, t);
    k_outpath<<<64,256,0,stream>>>(act, ao, bo, dec_o, oL, oR,
                                   opw1, opb1, opl1g, opl1b,
                                   opw2, opb2, opl2g, opl2b,
                                   opw3, opb3, outp, t);
  }
}

// Round 4
// 992.472 us; speedup vs baseline: 2.7389x; 1.5381x over previous
//
#include <hip/hip_runtime.h>
#include <math.h>

// Problem constants
constexpr int B_ = 64, N_ = 1024, M_ = 32, T_ = 8;
constexpr int OUT_ = 1000, NSO_ = 256;

#define DEVFN __device__ __forceinline__

DEVFN float blockReduceSum(float v, float* buf) {
  int t = threadIdx.x;
  buf[t] = v; __syncthreads();
  for (int off = blockDim.x >> 1; off > 0; off >>= 1) {
    if (t < off) buf[t] += buf[t + off];
    __syncthreads();
  }
  float r = buf[0];
  __syncthreads();
  return r;
}

DEVFN float blockReduceMax(float v, float* buf) {
  int t = threadIdx.x;
  buf[t] = v; __syncthreads();
  for (int off = blockDim.x >> 1; off > 0; off >>= 1) {
    if (t < off) buf[t] = fmaxf(buf[t], buf[t + off]);
    __syncthreads();
  }
  float r = buf[0];
  __syncthreads();
  return r;
}

DEVFN float sigmoidf_(float x) { return 1.f / (1.f + __expf(-x)); }

// ---------------- tiled conv 3x3 SAME, NCHW, input staged in LDS ----------------
// Block: one image b, TY output rows, all HW cols, all COUT channels.
// 256 threads = 64 spatial (XQ x-quads * TY rows) x 4 wave-uniform co-groups.
// MODE: 0 = raw input; 1 = bn+relu(in) via ssin; 2 = bn+relu+maxpool2 (in is 2HW x 2HW raw)
// Conv bias omitted everywhere: BatchNorm (train mode) immediately follows and is
// invariant to per-channel pre-shift (mean subtraction cancels it exactly); biases are 0 anyway.
template<int CIN, int COUT, int HW, int TY, int XV, int CICH, int MODE>
__global__ __launch_bounds__(256)
void k_conv_tiled(const float* __restrict__ in, const float* __restrict__ wgl,
                  const float2* __restrict__ ssin, float* __restrict__ outp) {
  constexpr int XQ = HW / XV;
  constexpr int NCG = 4;            // co-groups = waves
  constexpr int CPT = COUT / NCG;   // co per thread
  constexpr int PADW = HW + 8;      // 4 pad each side (alignment + halo)
  constexpr int NROW = TY + 2;
  constexpr int NCH = CIN / CICH;
  static_assert(XQ * TY == 64, "spatial threads per co-group must be 64");
  __shared__ __align__(16) float ins[CICH][NROW][PADW];

  const int b   = blockIdx.x;
  const int y0  = blockIdx.y * TY;
  const int tid = threadIdx.x;
  const int sp  = tid & 63;
  const int cg  = __builtin_amdgcn_readfirstlane(tid >> 6);  // wave-uniform -> scalar weight loads
  const int xq  = sp % XQ;
  const int yr  = sp / XQ;
  const int x0  = xq * XV;

  float acc[CPT][XV];
  #pragma unroll
  for (int j = 0; j < CPT; ++j)
    #pragma unroll
    for (int k = 0; k < XV; ++k) acc[j][k] = 0.f;

  for (int ch = 0; ch < NCH; ++ch) {
    const int ci0 = ch * CICH;
    __syncthreads();
    constexpr int NEL = CICH * NROW * PADW;
    for (int i = tid; i < NEL; i += 256) {
      int col = i % PADW;
      int row = (i / PADW) % NROW;
      int ci  = i / (PADW * NROW);
      int gx = col - 4;
      int gy = y0 + row - 1;
      float v = 0.f;
      if (gx >= 0 && gx < HW && gy >= 0 && gy < HW) {
        if (MODE == 0) {
          v = in[((size_t)(b * CIN + ci0 + ci) * HW + gy) * HW + gx];
        } else if (MODE == 1) {
          float2 s = ssin[ci0 + ci];
          v = fmaxf(fmaf(in[((size_t)(b * CIN + ci0 + ci) * HW + gy) * HW + gx], s.x, s.y), 0.f);
        } else {
          float2 s = ssin[ci0 + ci];
          const float* p = in + ((size_t)(b * CIN + ci0 + ci) * (2 * HW) + 2 * gy) * (2 * HW) + 2 * gx;
          float v0 = fmaf(p[0],          s.x, s.y);
          float v1 = fmaf(p[1],          s.x, s.y);
          float v2 = fmaf(p[2 * HW],     s.x, s.y);
          float v3 = fmaf(p[2 * HW + 1], s.x, s.y);
          v = fmaxf(fmaxf(fmaxf(v0, v1), fmaxf(v2, v3)), 0.f);
        }
      }
      ins[ci][row][col] = v;
    }
    __syncthreads();

    for (int ci = 0; ci < CICH; ++ci) {
      const float* wci = wgl + ((size_t)(cg * CPT) * CIN + (ci0 + ci)) * 9;
      #pragma unroll
      for (int dy = 0; dy < 3; ++dy) {
        const float* r = &ins[ci][yr + dy][x0 + 4];
        float win[XV + 2];
        win[0] = r[-1];
        if constexpr (XV == 4) {
          float4 m = *reinterpret_cast<const float4*>(r);
          win[1] = m.x; win[2] = m.y; win[3] = m.z; win[4] = m.w;
        } else {
          float2 m = *reinterpret_cast<const float2*>(r);
          win[1] = m.x; win[2] = m.y;
        }
        win[XV + 1] = r[XV];
        #pragma unroll
        for (int j = 0; j < CPT; ++j) {
          const float* wj = wci + (size_t)j * CIN * 9 + dy * 3;
          float w0 = wj[0], w1 = wj[1], w2 = wj[2];
          #pragma unroll
          for (int k = 0; k < XV; ++k)
            acc[j][k] = fmaf(win[k], w0, fmaf(win[k + 1], w1, fmaf(win[k + 2], w2, acc[j][k])));
        }
      }
    }
  }

  #pragma unroll
  for (int j = 0; j < CPT; ++j) {
    float* op = outp + (((size_t)b * COUT + cg * CPT + j) * HW + y0 + yr) * HW + x0;
    if constexpr (XV == 4)
      *reinterpret_cast<float4*>(op) = make_float4(acc[j][0], acc[j][1], acc[j][2], acc[j][3]);
    else
      *reinterpret_cast<float2*>(op) = make_float2(acc[j][0], acc[j][1]);
  }
}

// ---------------- BatchNorm (train mode) statistics ----------------
template<int C, int HW2>
__global__ __launch_bounds__(256)
void k_bn_stats(const float* __restrict__ x, float* __restrict__ part) {
  int c = blockIdx.x, s = blockIdx.y, ns = gridDim.y;
  const int Npc = B_ * HW2;
  float s1 = 0.f, s2 = 0.f;
  for (int ii = s * 256 + threadIdx.x; ii < Npc; ii += ns * 256) {
    int b = ii / HW2, pos = ii % HW2;
    float v = x[((size_t)b * C + c) * HW2 + pos];
    s1 += v; s2 += v * v;
  }
  __shared__ float r1[256], r2[256];
  r1[threadIdx.x] = s1; r2[threadIdx.x] = s2; __syncthreads();
  for (int off = 128; off > 0; off >>= 1) {
    if (threadIdx.x < off) { r1[threadIdx.x] += r1[threadIdx.x + off]; r2[threadIdx.x] += r2[threadIdx.x + off]; }
    __syncthreads();
  }
  if (threadIdx.x == 0) {
    part[(c * ns + s) * 2 + 0] = r1[0];
    part[(c * ns + s) * 2 + 1] = r2[0];
  }
}

__global__ void k_bn_finalize(const float* __restrict__ part, int C, int ns, float inv_n,
                              const float* __restrict__ g, const float* __restrict__ bb,
                              float2* __restrict__ ss) {
  int c = threadIdx.x;
  if (c >= C) return;
  float s1 = 0.f, s2 = 0.f;
  for (int s = 0; s < ns; ++s) { s1 += part[(c * ns + s) * 2]; s2 += part[(c * ns + s) * 2 + 1]; }
  float m = s1 * inv_n;
  float var = s2 * inv_n - m * m;
  float rstd = rsqrtf(var + 1e-5f);
  float sc = g[c] * rstd;
  ss[c] = make_float2(sc, bb[c] - m * sc);
}

// ---------------- bn4 + relu + adaptive avg pool (8x8 blocks) fused ----------------
__global__ __launch_bounds__(256)
void k_avgpool_bn(const float* __restrict__ x, const float2* __restrict__ ss,
                  float* __restrict__ outp) {
  int idx = blockIdx.x * 256 + threadIdx.x;   // B*256
  if (idx >= B_ * 256) return;
  int b = idx >> 8;
  int r = idx & 255;
  int c = r >> 2, i = (r >> 1) & 1, j = r & 1;
  float2 s = ss[c];
  const float* p = x + ((size_t)(b * 64 + c) * 16 + i * 8) * 16 + j * 8;
  float sum = 0.f;
  #pragma unroll
  for (int yy = 0; yy < 8; ++yy)
    #pragma unroll
    for (int xx = 0; xx < 8; ++xx) sum += fmaxf(fmaf(p[yy * 16 + xx], s.x, s.y), 0.f);
  outp[idx] = sum * (1.f / 64.f);
}

// ---------------- split-K GEMM: A(64 x K) @ W(K x NOUT) -> partials ----------------
template<int K, int NOUT>
__global__ __launch_bounds__(256)
void k_gemm_part(const float* __restrict__ A, const float* __restrict__ W, int ldw,
                 float* __restrict__ part) {
  int jt = blockIdx.x, ks = blockIdx.y;
  int k0 = ks * 64;
  __shared__ float As[64][65];
  for (int i = threadIdx.x; i < 4096; i += 256) {
    int r = i >> 6, c = i & 63;
    As[r][c] = A[(size_t)r * K + k0 + c];
  }
  __syncthreads();
  int jsub = threadIdx.x & 31;
  int bg = threadIdx.x >> 5;    // 0..7, 8 rows each
  int j = jt * 32 + jsub;
  float acc[8] = {0.f, 0.f, 0.f, 0.f, 0.f, 0.f, 0.f, 0.f};
  const float* wp = W + (size_t)k0 * ldw + j;
  #pragma unroll 8
  for (int kk = 0; kk < 64; ++kk) {
    float w = wp[(size_t)kk * ldw];
    #pragma unroll
    for (int r = 0; r < 8; ++r) acc[r] = fmaf(As[bg * 8 + r][kk], w, acc[r]);
  }
  float* pp = part + (size_t)ks * 64 * NOUT + j;
  #pragma unroll
  for (int r = 0; r < 8; ++r) pp[(size_t)(bg * 8 + r) * NOUT] = acc[r];
}

// ---------------- reduce partials + bias (+GLU) (+LN) ----------------
template<int NOUT, int NO_FIN, int KS, bool GLU_, bool LN_>
__global__ __launch_bounds__(256)
void k_fc_reduce(const float* __restrict__ part, const float* __restrict__ bias, int bstride,
                 const float* __restrict__ lng, const float* __restrict__ lnb,
                 float* __restrict__ outp) {
  constexpr int R = (NO_FIN + 255) / 256;
  int b = blockIdx.x, t = threadIdx.x;
  const float* bp = bias + (size_t)b * bstride;
  float v[R];
  #pragma unroll
  for (int r = 0; r < R; ++r) {
    int j = t + r * 256;
    if (j < NO_FIN) {
      float za = bp[j];
      float zb = GLU_ ? bp[j + NO_FIN] : 0.f;
      #pragma unroll
      for (int ks = 0; ks < KS; ++ks) {
        const float* pr = part + ((size_t)ks * 64 + b) * NOUT;
        za += pr[j];
        if (GLU_) zb += pr[j + NO_FIN];
      }
      v[r] = GLU_ ? za * sigmoidf_(zb) : za;
    } else v[r] = 0.f;
  }
  if (LN_) {
    __shared__ float red[256];
    float s1 = 0.f, s2 = 0.f;
    #pragma unroll
    for (int r = 0; r < R; ++r) { s1 += v[r]; s2 += v[r] * v[r]; }
    s1 = blockReduceSum(s1, red);
    s2 = blockReduceSum(s2, red);
    float mu = s1 / (float)NO_FIN;
    float rstd = rsqrtf(s2 / (float)NO_FIN - mu * mu + 1e-5f);
    #pragma unroll
    for (int r = 0; r < R; ++r) {
      int j = t + r * 256;
      if (j < NO_FIN) outp[(size_t)b * NO_FIN + j] = fmaf((v[r] - mu) * rstd, lng[j], lnb[j]);
    }
  } else {
    #pragma unroll
    for (int r = 0; r < R; ++r) {
      int j = t + r * 256;
      if (j < NO_FIN) outp[(size_t)b * NO_FIN + j] = v[r];
    }
  }
}

// ---------------- recurrent state init ----------------
__global__ __launch_bounds__(256)
void k_init(const float* __restrict__ sa, const float* __restrict__ st,
            const int* __restrict__ oL, const int* __restrict__ oR,
            float* __restrict__ act, float* __restrict__ trace,
            float* __restrict__ ao, float* __restrict__ bo) {
  int idx = blockIdx.x * 256 + threadIdx.x;
  if (idx < B_ * N_ * M_) trace[idx] = st[idx % (N_ * M_)];
  if (idx < B_ * N_)      act[idx]   = sa[idx % N_];
  if (idx < B_ * NSO_) {
    int i = idx % NSO_;
    ao[idx] = sa[oL[i]] * sa[oR[i]];
    bo[idx] = 1.f;
  }
}

// ---------------- per-tick: LN + append to trace ring (slot) ----------------
__global__ __launch_bounds__(256)
void k_ln_trace(const float* __restrict__ sraw, const float* __restrict__ g,
                const float* __restrict__ bb, float* __restrict__ trace, int slot) {
  int b = blockIdx.x, t = threadIdx.x;
  __shared__ float red[256];
  float v[4]; float s1 = 0.f, s2 = 0.f;
  #pragma unroll
  for (int r = 0; r < 4; ++r) {
    v[r] = sraw[b * 1024 + t + r * 256];
    s1 += v[r]; s2 += v[r] * v[r];
  }
  s1 = blockReduceSum(s1, red);
  s2 = blockReduceSum(s2, red);
  float mu = s1 * (1.f / 1024.f);
  float rstd = rsqrtf(s2 * (1.f / 1024.f) - mu * mu + 1e-5f);
  #pragma unroll
  for (int r = 0; r < 4; ++r) {
    int n = t + r * 256;
    trace[((size_t)b * N_ + n) * M_ + slot] = fmaf((v[r] - mu) * rstd, g[n], bb[n]);
  }
}

// ---------------- per-tick: per-neuron private MLP ----------------
__global__ __launch_bounds__(128)
void k_nlm(const float* __restrict__ trace, const float* __restrict__ w1,
           const float* __restrict__ b1, const float* __restrict__ w2,
           const float* __restrict__ b2, float* __restrict__ act, int tick) {
  int n = blockIdx.x, t = threadIdx.x;
  __shared__ float tr[64][32];
  __shared__ float hid[128][65];
  __shared__ float comb[64];
  for (int k = t; k < 64 * 32; k += 128) {
    int b = k >> 5, m = k & 31;
    tr[b][m] = trace[((size_t)b * N_ + n) * M_ + m];
  }
  const float* wp = w1 + (size_t)n * (M_ * 256);
  float wa[32], wb[32];
  #pragma unroll
  for (int ms = 0; ms < 32; ++ms) {
    int m = (ms - tick - 1) & 31;
    wa[ms] = wp[m * 256 + t];
    wb[ms] = wp[m * 256 + 128 + t];
  }
  float ba = b1[n * 256 + t];
  float bgt = b1[n * 256 + 128 + t];
  float w2v = w2[n * 128 + t];
  __syncthreads();
  for (int b = 0; b < 64; ++b) {
    const float4* trb = reinterpret_cast<const float4*>(&tr[b][0]);
    float za = ba, zb = bgt;
    #pragma unroll
    for (int q = 0; q < 8; ++q) {
      float4 v = trb[q];
      za = fmaf(v.x, wa[4*q+0], za); zb = fmaf(v.x, wb[4*q+0], zb);
      za = fmaf(v.y, wa[4*q+1], za); zb = fmaf(v.y, wb[4*q+1], zb);
      za = fmaf(v.z, wa[4*q+2], za); zb = fmaf(v.z, wb[4*q+2], zb);
      za = fmaf(v.w, wa[4*q+3], za); zb = fmaf(v.w, wb[4*q+3], zb);
    }
    hid[t][b] = za * sigmoidf_(zb) * w2v;
  }
  __syncthreads();
  int bb2 = t & 63, half = t >> 6;
  float s = 0.f;
  #pragma unroll 8
  for (int q = 0; q < 64; ++q) s += hid[half * 64 + q][bb2];
  if (half == 1) comb[bb2] = s;
  __syncthreads();
  if (half == 0) act[(size_t)bb2 * N_ + n] = s + comb[bb2] + b2[n];
}

// ---------------- per-tick: sync_o + output MLP + pred + cert ----------------
__global__ __launch_bounds__(256)
void k_outpath(const float* __restrict__ act, float* __restrict__ ao, float* __restrict__ bo,
               const float* __restrict__ dec_o, const int* __restrict__ oL, const int* __restrict__ oR,
               const float* __restrict__ opw1, const float* __restrict__ opb1,
               const float* __restrict__ l1g, const float* __restrict__ l1b,
               const float* __restrict__ opw2, const float* __restrict__ opb2,
               const float* __restrict__ l2g, const float* __restrict__ l2b,
               const float* __restrict__ opw3, const float* __restrict__ opb3,
               float* __restrict__ outp, int tick) {
  int b = blockIdx.x, t = threadIdx.x;
  __shared__ float red[256];
  __shared__ float syo[256], h1s[256], h2s[64];
  const float* actb = act + (size_t)b * 1024;
  float po = actb[oL[t]] * actb[oR[t]];
  float r = __expf(-fminf(fmaxf(dec_o[t], 0.f), 15.f));
  int ai = b * 256 + t;
  float av = fmaf(r, ao[ai], po);
  float bv = fmaf(r, bo[ai], 1.f);
  ao[ai] = av; bo[ai] = bv;
  syo[t] = av * rsqrtf(bv + 1e-8f);
  __syncthreads();
  float z = opb1[t];
  for (int k = 0; k < 256; ++k) z = fmaf(syo[k], opw1[k * 256 + t], z);
  float s1 = blockReduceSum(z, red);
  float s2 = blockReduceSum(z * z, red);
  float mu = s1 * (1.f / 256.f);
  float rstd = rsqrtf(s2 * (1.f / 256.f) - mu * mu + 1e-5f);
  h1s[t] = fmaxf(fmaf((z - mu) * rstd, l1g[t], l1b[t]), 0.f);
  __syncthreads();
  if (t < 64) {
    float z2 = opb2[t];
    for (int k = 0; k < 256; ++k) z2 = fmaf(h1s[k], opw2[k * 64 + t], z2);
    float a1 = z2, a2 = z2 * z2;
    #pragma unroll
    for (int o = 32; o > 0; o >>= 1) { a1 += __shfl_xor(a1, o); a2 += __shfl_xor(a2, o); }
    float mu2 = a1 * (1.f / 64.f);
    float rs2 = rsqrtf(a2 * (1.f / 64.f) - mu2 * mu2 + 1e-5f);
    h2s[t] = fmaxf(fmaf((z2 - mu2) * rs2, l2g[t], l2b[t]), 0.f);
  }
  __syncthreads();
  float zp[4];
  float mymax = -INFINITY;
  #pragma unroll
  for (int g2 = 0; g2 < 4; ++g2) {
    int j = t + g2 * 256;
    if (j < OUT_) {
      float z3 = opb3[j];
      for (int k = 0; k < 64; ++k) z3 = fmaf(h2s[k], opw3[k * OUT_ + j], z3);
      outp[(size_t)b * (OUT_ * T_) + (size_t)j * T_ + tick] = z3;
      zp[g2] = z3;
      mymax = fmaxf(mymax, z3);
    } else zp[g2] = -INFINITY;
  }
  float mx = blockReduceMax(mymax, red);
  float es = 0.f;
  #pragma unroll
  for (int g2 = 0; g2 < 4; ++g2) {
    if (t + g2 * 256 < OUT_) { zp[g2] = __expf(zp[g2] - mx); es += zp[g2]; }
    else zp[g2] = 0.f;
  }
  float S = blockReduceSum(es, red);
  float inv = 1.f / S;
  float ep = 0.f;
  #pragma unroll
  for (int g2 = 0; g2 < 4; ++g2) {
    if (t + g2 * 256 < OUT_) {
      float p = zp[g2] * inv;
      ep += p * __logf(p + 1e-10f);
    }
  }
  float ent = -blockReduceSum(ep, red);
  if (t == 0) {
    float ne = ent * (1.f / logf(1000.f));
    outp[(size_t)B_ * OUT_ * T_ + (size_t)b * 2 * T_ + tick]      = ne;
    outp[(size_t)B_ * OUT_ * T_ + (size_t)b * 2 * T_ + T_ + tick] = 1.f - ne;
  }
}

extern "C" void kernel_launch(void* const* d_in, const int* in_sizes, int n_in,
                              void* d_out, int out_size, void* d_ws, size_t ws_size,
                              hipStream_t stream) {
  (void)in_sizes; (void)n_in; (void)out_size; (void)ws_size;
  const float* x      = (const float*)d_in[0];
  const float* c1w    = (const float*)d_in[1];
  const float* bn1g   = (const float*)d_in[3];
  const float* bn1b   = (const float*)d_in[4];
  const float* c2w    = (const float*)d_in[5];
  const float* bn2g   = (const float*)d_in[7];
  const float* bn2b   = (const float*)d_in[8];
  const float* c3w    = (const float*)d_in[9];
  const float* bn3g   = (const float*)d_in[11];
  const float* bn3b   = (const float*)d_in[12];
  const float* c4w    = (const float*)d_in[13];
  const float* bn4g   = (const float*)d_in[15];
  const float* bn4b   = (const float*)d_in[16];
  const float* fc1w   = (const float*)d_in[17];
  const float* fc1b   = (const float*)d_in[18];
  const float* fc2w   = (const float*)d_in[19];
  const float* fc2b   = (const float*)d_in[20];
  const float* kvw    = (const float*)d_in[21];
  const float* kvb    = (const float*)d_in[22];
  const float* kvlg   = (const float*)d_in[23];
  const float* kvlb   = (const float*)d_in[24];
  const float* synw   = (const float*)d_in[25];
  const float* synb   = (const float*)d_in[26];
  const float* synlg  = (const float*)d_in[27];
  const float* synlb  = (const float*)d_in[28];
  const float* nlmw1  = (const float*)d_in[29];
  const float* nlmb1  = (const float*)d_in[30];
  const float* nlmw2  = (const float*)d_in[31];
  const float* nlmb2  = (const float*)d_in[32];
  const float* sact   = (const float*)d_in[33];
  const float* strc   = (const float*)d_in[34];
  const float* dec_o  = (const float*)d_in[36];
  const float* attn_inw = (const float*)d_in[39];
  const float* attn_inb = (const float*)d_in[40];
  const float* attn_ow  = (const float*)d_in[41];
  const float* attn_ob  = (const float*)d_in[42];
  const float* opw1   = (const float*)d_in[43];
  const float* opb1   = (const float*)d_in[44];
  const float* opl1g  = (const float*)d_in[45];
  const float* opl1b  = (const float*)d_in[46];
  const float* opw2   = (const float*)d_in[47];
  const float* opb2   = (const float*)d_in[48];
  const float* opl2g  = (const float*)d_in[49];
  const float* opl2b  = (const float*)d_in[50];
  const float* opw3   = (const float*)d_in[51];
  const float* opb3   = (const float*)d_in[52];
  const int*   oL     = (const int*)d_in[55];
  const int*   oR     = (const int*)d_in[56];
  float* outp = (float*)d_out;
  float* ws   = (float*)d_ws;

  // workspace layout (floats).
  // c2raw occupies [4,194,304 , 12,582,912) during the conv phase — ONLY buffers
  // dead during that window may alias it (part/trace/act/... are used strictly
  // after conv3 consumed c2raw). bnpart/bnss are LIVE during convs -> placed
  // ABOVE 12,582,912. Total 12,587,136 floats = 50.3 MB.
  float* c1raw = ws;                    // 4,194,304 (64x16x64x64); later c3raw
  float* c3raw = ws;                    //   (conv3 out reuses after c1raw dead)
  float* c2raw = ws + 4194304;          // 8,388,608 (64x32x64x64)
  float* c4raw = ws + 4194304;          // 1,048,576 (reuses c2raw head after conv3)
  float* part  = ws + 5242880;          // 2,097,152 split-K partials (post-conv only)
  float* trace = ws + 7340032;          // 2,097,152 (post-conv only)
  float* act   = ws + 9437184;          // 65,536
  float* sraw  = ws + 9502720;          // 65,536
  float* syncst= ws + 9568256;          // 131,072
  float* pooled= ws + 9699328;          // 16,384
  float* ench  = ws + 9715712;          // 8,192
  float* enc   = ws + 9723904;          // 32,768
  float* kvbuf = ws + 9756672;          // 32,768
  float* vhbuf = ws + 9789440;          // 32,768
  float* aout  = ws + 9822208;          // 32,768
  float* ao    = ws + 9854976;          // 16,384
  float* bo    = ws + 9871360;          // 16,384
  float* bnpart= ws + 12582912;         // 4,096   (live during convs -> outside c2raw)
  float2* bnss = (float2*)(ws + 12587008); // 64 float2 (live during convs -> outside c2raw)

  // ---- encoder convs (BN-apply of layer L fused into conv L+1 staging) ----
  k_conv_tiled<3,16,64,4,4,3,0><<<dim3(64,16),256,0,stream>>>(x, c1w, nullptr, c1raw);
  k_bn_stats<16,4096><<<dim3(16,32),256,0,stream>>>(c1raw, bnpart);
  k_bn_finalize<<<1,64,0,stream>>>(bnpart, 16, 32, 1.f/(float)(B_*4096), bn1g, bn1b, bnss);

  k_conv_tiled<16,32,64,4,4,16,1><<<dim3(64,16),256,0,stream>>>(c1raw, c2w, bnss, c2raw);
  k_bn_stats<32,4096><<<dim3(32,32),256,0,stream>>>(c2raw, bnpart);
  k_bn_finalize<<<1,64,0,stream>>>(bnpart, 32, 32, 1.f/(float)(B_*4096), bn2g, bn2b, bnss);

  k_conv_tiled<32,64,32,8,4,16,2><<<dim3(64,4),256,0,stream>>>(c2raw, c3w, bnss, c3raw);
  k_bn_stats<64,1024><<<dim3(64,16),256,0,stream>>>(c3raw, bnpart);
  k_bn_finalize<<<1,64,0,stream>>>(bnpart, 64, 16, 1.f/(float)(B_*1024), bn3g, bn3b, bnss);

  k_conv_tiled<64,64,16,8,2,16,2><<<dim3(64,2),256,0,stream>>>(c3raw, c4w, bnss, c4raw);
  k_bn_stats<64,256><<<dim3(64,8),256,0,stream>>>(c4raw, bnpart);
  k_bn_finalize<<<1,64,0,stream>>>(bnpart, 64, 8, 1.f/(float)(B_*256), bn4g, bn4b, bnss);

  k_avgpool_bn<<<64,256,0,stream>>>(c4raw, bnss, pooled);

  // ---- encoder FC chain (split-K GEMM + fused reduce) ----
  k_gemm_part<256,256><<<dim3(8,4),256,0,stream>>>(pooled, fc1w, 256, part);
  k_fc_reduce<256,128,4,true,false><<<64,256,0,stream>>>(part, fc1b, 0, nullptr, nullptr, ench);
  k_gemm_part<128,512><<<dim3(16,2),256,0,stream>>>(ench, fc2w, 512, part);
  k_fc_reduce<512,512,2,false,false><<<64,256,0,stream>>>(part, fc2b, 0, nullptr, nullptr, enc);
  k_gemm_part<512,512><<<dim3(16,8),256,0,stream>>>(enc, kvw, 512, part);
  k_fc_reduce<512,512,8,false,true><<<64,256,0,stream>>>(part, kvb, 0, kvlg, kvlb, kvbuf);
  // vh = kv @ Wv + bv (attention softmax over single key == 1 -> q,k branches dead)
  k_gemm_part<512,512><<<dim3(16,8),256,0,stream>>>(kvbuf, attn_inw + 1024, 1536, part);
  k_fc_reduce<512,512,8,false,false><<<64,256,0,stream>>>(part, attn_inb + 1024, 0, nullptr, nullptr, vhbuf);
  k_gemm_part<512,512><<<dim3(16,8),256,0,stream>>>(vhbuf, attn_ow, 512, part);
  k_fc_reduce<512,512,8,false,false><<<64,256,0,stream>>>(part, attn_ob, 0, nullptr, nullptr, aout);
  k_gemm_part<512,2048><<<dim3(64,8),256,0,stream>>>(aout, synw, 2048, part);
  k_fc_reduce<2048,2048,8,false,false><<<64,256,0,stream>>>(part, synb, 0, nullptr, nullptr, syncst);

  k_init<<<8192,256,0,stream>>>(sact, strc, oL, oR, act, trace, ao, bo);

  // ---- recurrent ticks ----
  for (int t = 0; t < T_; ++t) {
    k_gemm_part<1024,2048><<<dim3(64,16),256,0,stream>>>(act, synw + (size_t)512 * 2048, 2048, part);
    k_fc_reduce<2048,1024,16,true,false><<<64,256,0,stream>>>(part, syncst, 2048, nullptr, nullptr, sraw);
    k_ln_trace<<<64,256,0,stream>>>(sraw, synlg, synlb, trace, t);
    k_nlm<<<1024,128,0,stream>>>(trace, nlmw1, nlmb1, nlmw2, nlmb2, act, t);
    k_outpath<<<64,256,0,stream>>>(act, ao, bo, dec_o, oL, oR,
                                   opw1, opb1, opl1g, opl1b,
                                   opw2, opb2, opl2g, opl2b,
                                   opw3, opb3, outp, t);
  }
}

// Round 5
// 912.463 us; speedup vs baseline: 2.9791x; 1.0877x over previous
//
#include <hip/hip_runtime.h>
#include <math.h>

// Problem constants
constexpr int B_ = 64, N_ = 1024, M_ = 32, T_ = 8;
constexpr int OUT_ = 1000, NSO_ = 256;

#define DEVFN __device__ __forceinline__

DEVFN float blockReduceSum(float v, float* buf) {
  int t = threadIdx.x;
  buf[t] = v; __syncthreads();
  for (int off = blockDim.x >> 1; off > 0; off >>= 1) {
    if (t < off) buf[t] += buf[t + off];
    __syncthreads();
  }
  float r = buf[0];
  __syncthreads();
  return r;
}

DEVFN float blockReduceMax(float v, float* buf) {
  int t = threadIdx.x;
  buf[t] = v; __syncthreads();
  for (int off = blockDim.x >> 1; off > 0; off >>= 1) {
    if (t < off) buf[t] = fmaxf(buf[t], buf[t + off]);
    __syncthreads();
  }
  float r = buf[0];
  __syncthreads();
  return r;
}

DEVFN float sigmoidf_(float x) { return 1.f / (1.f + __expf(-x)); }

// ---------------- tiled conv 3x3 SAME, NCHW, input staged in LDS ----------------
// Block: one image b, TY output rows, all HW cols, all COUT channels, CIN/KSPLIT input chans.
// 256 threads = 64 spatial (XQ x-quads * TY rows) x 4 wave-uniform co-groups.
// MODE: 0 = raw input; 1 = bn+relu(in) via ssin; 2 = bn+relu+maxpool2 (in is 2HW x 2HW raw)
// KSPLIT>1: blockIdx.z selects a CIN chunk; output written to partial buffer slice ks.
// Conv bias omitted: BatchNorm (train) follows and cancels per-channel pre-shift (biases are 0 anyway).
template<int CIN, int COUT, int HW, int TY, int XV, int CICH, int MODE, int KSPLIT>
__global__ __launch_bounds__(256)
void k_conv_tiled(const float* __restrict__ in, const float* __restrict__ wgl,
                  const float2* __restrict__ ssin, float* __restrict__ outp) {
  constexpr int XQ = HW / XV;
  constexpr int NCG = 4;            // co-groups = waves
  constexpr int CPT = COUT / NCG;   // co per thread
  constexpr int PADW = HW + 8;      // 4 pad each side (alignment + halo)
  constexpr int NROW = TY + 2;
  constexpr int CINB = CIN / KSPLIT;
  constexpr int NCH = CINB / CICH;
  static_assert(XQ * TY == 64, "spatial threads per co-group must be 64");
  __shared__ __align__(16) float ins[CICH][NROW][PADW];

  const int b   = blockIdx.x;
  const int y0  = blockIdx.y * TY;
  const int ks  = (KSPLIT > 1) ? blockIdx.z : 0;
  const int tid = threadIdx.x;
  const int sp  = tid & 63;
  const int cg  = __builtin_amdgcn_readfirstlane(tid >> 6);  // wave-uniform -> scalar weight loads
  const int xq  = sp % XQ;
  const int yr  = sp / XQ;
  const int x0  = xq * XV;

  float acc[CPT][XV];
  #pragma unroll
  for (int j = 0; j < CPT; ++j)
    #pragma unroll
    for (int k = 0; k < XV; ++k) acc[j][k] = 0.f;

  for (int ch = 0; ch < NCH; ++ch) {
    const int ci0 = ks * CINB + ch * CICH;
    __syncthreads();
    constexpr int NEL = CICH * NROW * PADW;
    for (int i = tid; i < NEL; i += 256) {
      int col = i % PADW;
      int row = (i / PADW) % NROW;
      int ci  = i / (PADW * NROW);
      int gx = col - 4;
      int gy = y0 + row - 1;
      float v = 0.f;
      if (gx >= 0 && gx < HW && gy >= 0 && gy < HW) {
        if (MODE == 0) {
          v = in[((size_t)(b * CIN + ci0 + ci) * HW + gy) * HW + gx];
        } else if (MODE == 1) {
          float2 s = ssin[ci0 + ci];
          v = fmaxf(fmaf(in[((size_t)(b * CIN + ci0 + ci) * HW + gy) * HW + gx], s.x, s.y), 0.f);
        } else {
          float2 s = ssin[ci0 + ci];
          const float* p = in + ((size_t)(b * CIN + ci0 + ci) * (2 * HW) + 2 * gy) * (2 * HW) + 2 * gx;
          float v0 = fmaf(p[0],          s.x, s.y);
          float v1 = fmaf(p[1],          s.x, s.y);
          float v2 = fmaf(p[2 * HW],     s.x, s.y);
          float v3 = fmaf(p[2 * HW + 1], s.x, s.y);
          v = fmaxf(fmaxf(fmaxf(v0, v1), fmaxf(v2, v3)), 0.f);
        }
      }
      ins[ci][row][col] = v;
    }
    __syncthreads();

    for (int ci = 0; ci < CICH; ++ci) {
      const float* wci = wgl + ((size_t)(cg * CPT) * CIN + (ci0 + ci)) * 9;
      #pragma unroll
      for (int dy = 0; dy < 3; ++dy) {
        const float* r = &ins[ci][yr + dy][x0 + 4];
        float win[XV + 2];
        win[0] = r[-1];
        if constexpr (XV == 4) {
          float4 m = *reinterpret_cast<const float4*>(r);
          win[1] = m.x; win[2] = m.y; win[3] = m.z; win[4] = m.w;
        } else {
          float2 m = *reinterpret_cast<const float2*>(r);
          win[1] = m.x; win[2] = m.y;
        }
        win[XV + 1] = r[XV];
        #pragma unroll
        for (int j = 0; j < CPT; ++j) {
          const float* wj = wci + (size_t)j * CIN * 9 + dy * 3;
          float w0 = wj[0], w1 = wj[1], w2 = wj[2];
          #pragma unroll
          for (int k = 0; k < XV; ++k)
            acc[j][k] = fmaf(win[k], w0, fmaf(win[k + 1], w1, fmaf(win[k + 2], w2, acc[j][k])));
        }
      }
    }
  }

  const size_t pofs = (size_t)ks * B_ * COUT * HW * HW;
  #pragma unroll
  for (int j = 0; j < CPT; ++j) {
    float* op = outp + pofs + (((size_t)b * COUT + cg * CPT + j) * HW + y0 + yr) * HW + x0;
    if constexpr (XV == 4)
      *reinterpret_cast<float4*>(op) = make_float4(acc[j][0], acc[j][1], acc[j][2], acc[j][3]);
    else
      *reinterpret_cast<float2*>(op) = make_float2(acc[j][0], acc[j][1]);
  }
}

// ---------------- BatchNorm (train mode) statistics, over sum of NS partials ----------------
template<int C, int HW2, int NS>
__global__ __launch_bounds__(256)
void k_bn_stats(const float* __restrict__ x, float* __restrict__ part) {
  int c = blockIdx.x, s = blockIdx.y, ns = gridDim.y;
  const int Npc = B_ * HW2;
  constexpr size_t PSTR = (size_t)B_ * C * HW2;
  float s1 = 0.f, s2 = 0.f;
  for (int ii = s * 256 + threadIdx.x; ii < Npc; ii += ns * 256) {
    int b = ii / HW2, pos = ii % HW2;
    size_t base = ((size_t)b * C + c) * HW2 + pos;
    float v = x[base];
    #pragma unroll
    for (int q = 1; q < NS; ++q) v += x[base + q * PSTR];
    s1 += v; s2 += v * v;
  }
  __shared__ float r1[256], r2[256];
  r1[threadIdx.x] = s1; r2[threadIdx.x] = s2; __syncthreads();
  for (int off = 128; off > 0; off >>= 1) {
    if (threadIdx.x < off) { r1[threadIdx.x] += r1[threadIdx.x + off]; r2[threadIdx.x] += r2[threadIdx.x + off]; }
    __syncthreads();
  }
  if (threadIdx.x == 0) {
    part[(c * ns + s) * 2 + 0] = r1[0];
    part[(c * ns + s) * 2 + 1] = r2[0];
  }
}

__global__ void k_bn_finalize(const float* __restrict__ part, int C, int ns, float inv_n,
                              const float* __restrict__ g, const float* __restrict__ bb,
                              float2* __restrict__ ss) {
  int c = threadIdx.x;
  if (c >= C) return;
  float s1 = 0.f, s2 = 0.f;
  for (int s = 0; s < ns; ++s) { s1 += part[(c * ns + s) * 2]; s2 += part[(c * ns + s) * 2 + 1]; }
  float m = s1 * inv_n;
  float var = s2 * inv_n - m * m;
  float rstd = rsqrtf(var + 1e-5f);
  float sc = g[c] * rstd;
  ss[c] = make_float2(sc, bb[c] - m * sc);
}

// ---------------- (sum 4 partials) + bn4 + relu + adaptive avg pool fused ----------------
__global__ __launch_bounds__(256)
void k_avgpool_bn(const float* __restrict__ x, const float2* __restrict__ ss,
                  float* __restrict__ outp) {
  constexpr size_t PSTR = (size_t)B_ * 64 * 256;
  int idx = blockIdx.x * 256 + threadIdx.x;   // B*256
  if (idx >= B_ * 256) return;
  int b = idx >> 8;
  int r = idx & 255;
  int c = r >> 2, i = (r >> 1) & 1, j = r & 1;
  float2 s = ss[c];
  const float* p = x + ((size_t)(b * 64 + c) * 16 + i * 8) * 16 + j * 8;
  float sum = 0.f;
  #pragma unroll
  for (int yy = 0; yy < 8; ++yy)
    #pragma unroll
    for (int xx = 0; xx < 8; ++xx) {
      size_t o = yy * 16 + xx;
      float v = p[o] + p[o + PSTR] + p[o + 2 * PSTR] + p[o + 3 * PSTR];
      sum += fmaxf(fmaf(v, s.x, s.y), 0.f);
    }
  outp[idx] = sum * (1.f / 64.f);
}

// ---------------- split-K GEMM: A(64 x K) @ W(K x NOUT) -> partials ----------------
template<int K, int NOUT>
__global__ __launch_bounds__(256)
void k_gemm_part(const float* __restrict__ A, const float* __restrict__ W, int ldw,
                 float* __restrict__ part) {
  int jt = blockIdx.x, ks = blockIdx.y;
  int k0 = ks * 64;
  __shared__ float As[64][65];
  for (int i = threadIdx.x; i < 4096; i += 256) {
    int r = i >> 6, c = i & 63;
    As[r][c] = A[(size_t)r * K + k0 + c];
  }
  __syncthreads();
  int jsub = threadIdx.x & 31;
  int bg = threadIdx.x >> 5;    // 0..7, 8 rows each
  int j = jt * 32 + jsub;
  float acc[8] = {0.f, 0.f, 0.f, 0.f, 0.f, 0.f, 0.f, 0.f};
  const float* wp = W + (size_t)k0 * ldw + j;
  #pragma unroll 8
  for (int kk = 0; kk < 64; ++kk) {
    float w = wp[(size_t)kk * ldw];
    #pragma unroll
    for (int r = 0; r < 8; ++r) acc[r] = fmaf(As[bg * 8 + r][kk], w, acc[r]);
  }
  float* pp = part + (size_t)ks * 64 * NOUT + j;
  #pragma unroll
  for (int r = 0; r < 8; ++r) pp[(size_t)(bg * 8 + r) * NOUT] = acc[r];
}

// ---------------- reduce partials + bias (+GLU) (+LN) ----------------
template<int NOUT, int NO_FIN, int KS, bool GLU_, bool LN_>
__global__ __launch_bounds__(256)
void k_fc_reduce(const float* __restrict__ part, const float* __restrict__ bias, int bstride,
                 const float* __restrict__ lng, const float* __restrict__ lnb,
                 float* __restrict__ outp) {
  constexpr int R = (NO_FIN + 255) / 256;
  int b = blockIdx.x, t = threadIdx.x;
  const float* bp = bias + (size_t)b * bstride;
  float v[R];
  #pragma unroll
  for (int r = 0; r < R; ++r) {
    int j = t + r * 256;
    if (j < NO_FIN) {
      float za = bp[j];
      float zb = GLU_ ? bp[j + NO_FIN] : 0.f;
      #pragma unroll
      for (int ks = 0; ks < KS; ++ks) {
        const float* pr = part + ((size_t)ks * 64 + b) * NOUT;
        za += pr[j];
        if (GLU_) zb += pr[j + NO_FIN];
      }
      v[r] = GLU_ ? za * sigmoidf_(zb) : za;
    } else v[r] = 0.f;
  }
  if (LN_) {
    __shared__ float red[256];
    float s1 = 0.f, s2 = 0.f;
    #pragma unroll
    for (int r = 0; r < R; ++r) { s1 += v[r]; s2 += v[r] * v[r]; }
    s1 = blockReduceSum(s1, red);
    s2 = blockReduceSum(s2, red);
    float mu = s1 / (float)NO_FIN;
    float rstd = rsqrtf(s2 / (float)NO_FIN - mu * mu + 1e-5f);
    #pragma unroll
    for (int r = 0; r < R; ++r) {
      int j = t + r * 256;
      if (j < NO_FIN) outp[(size_t)b * NO_FIN + j] = fmaf((v[r] - mu) * rstd, lng[j], lnb[j]);
    }
  } else {
    #pragma unroll
    for (int r = 0; r < R; ++r) {
      int j = t + r * 256;
      if (j < NO_FIN) outp[(size_t)b * NO_FIN + j] = v[r];
    }
  }
}

// ---------------- per-tick: syn reduce = partials + syncst -> GLU -> LN -> trace ring ----------------
__global__ __launch_bounds__(256)
void k_syn_reduce(const float* __restrict__ part, const float* __restrict__ syncst,
                  const float* __restrict__ g, const float* __restrict__ bb,
                  float* __restrict__ trace, int slot) {
  int b = blockIdx.x, t = threadIdx.x;
  __shared__ float red[256];
  float v[4];
  #pragma unroll
  for (int r = 0; r < 4; ++r) {
    int j = t + r * 256;
    float za = syncst[b * 2048 + j];
    float zb = syncst[b * 2048 + 1024 + j];
    #pragma unroll
    for (int ks = 0; ks < 16; ++ks) {
      const float* pr = part + ((size_t)ks * 64 + b) * 2048;
      za += pr[j];
      zb += pr[j + 1024];
    }
    v[r] = za * sigmoidf_(zb);
  }
  float s1 = 0.f, s2 = 0.f;
  #pragma unroll
  for (int r = 0; r < 4; ++r) { s1 += v[r]; s2 += v[r] * v[r]; }
  s1 = blockReduceSum(s1, red);
  s2 = blockReduceSum(s2, red);
  float mu = s1 * (1.f / 1024.f);
  float rstd = rsqrtf(s2 * (1.f / 1024.f) - mu * mu + 1e-5f);
  #pragma unroll
  for (int r = 0; r < 4; ++r) {
    int n = t + r * 256;
    trace[((size_t)b * N_ + n) * M_ + slot] = fmaf((v[r] - mu) * rstd, g[n], bb[n]);
  }
}

// ---------------- recurrent state init ----------------
__global__ __launch_bounds__(256)
void k_init(const float* __restrict__ sa, const float* __restrict__ st,
            const int* __restrict__ oL, const int* __restrict__ oR,
            float* __restrict__ act, float* __restrict__ trace,
            float* __restrict__ ao, float* __restrict__ bo) {
  int idx = blockIdx.x * 256 + threadIdx.x;
  if (idx < B_ * N_ * M_) trace[idx] = st[idx % (N_ * M_)];
  if (idx < B_ * N_)      act[idx]   = sa[idx % N_];
  if (idx < B_ * NSO_) {
    int i = idx % NSO_;
    ao[idx] = sa[oL[i]] * sa[oR[i]];
    bo[idx] = 1.f;
  }
}

// ---------------- per-tick: per-neuron private MLP ----------------
__global__ __launch_bounds__(128)
void k_nlm(const float* __restrict__ trace, const float* __restrict__ w1,
           const float* __restrict__ b1, const float* __restrict__ w2,
           const float* __restrict__ b2, float* __restrict__ act, int tick) {
  int n = blockIdx.x, t = threadIdx.x;
  __shared__ float tr[64][32];
  __shared__ float hid[128][65];
  __shared__ float comb[64];
  for (int k = t; k < 64 * 32; k += 128) {
    int b = k >> 5, m = k & 31;
    tr[b][m] = trace[((size_t)b * N_ + n) * M_ + m];
  }
  const float* wp = w1 + (size_t)n * (M_ * 256);
  float wa[32], wb[32];
  #pragma unroll
  for (int ms = 0; ms < 32; ++ms) {
    int m = (ms - tick - 1) & 31;
    wa[ms] = wp[m * 256 + t];
    wb[ms] = wp[m * 256 + 128 + t];
  }
  float ba = b1[n * 256 + t];
  float bgt = b1[n * 256 + 128 + t];
  float w2v = w2[n * 128 + t];
  __syncthreads();
  for (int b = 0; b < 64; ++b) {
    const float4* trb = reinterpret_cast<const float4*>(&tr[b][0]);
    float za = ba, zb = bgt;
    #pragma unroll
    for (int q = 0; q < 8; ++q) {
      float4 v = trb[q];
      za = fmaf(v.x, wa[4*q+0], za); zb = fmaf(v.x, wb[4*q+0], zb);
      za = fmaf(v.y, wa[4*q+1], za); zb = fmaf(v.y, wb[4*q+1], zb);
      za = fmaf(v.z, wa[4*q+2], za); zb = fmaf(v.z, wb[4*q+2], zb);
      za = fmaf(v.w, wa[4*q+3], za); zb = fmaf(v.w, wb[4*q+3], zb);
    }
    hid[t][b] = za * sigmoidf_(zb) * w2v;
  }
  __syncthreads();
  int bb2 = t & 63, half = t >> 6;
  float s = 0.f;
  #pragma unroll 8
  for (int q = 0; q < 64; ++q) s += hid[half * 64 + q][bb2];
  if (half == 1) comb[bb2] = s;
  __syncthreads();
  if (half == 0) act[(size_t)bb2 * N_ + n] = s + comb[bb2] + b2[n];
}

// ---------------- per-tick: sync_o + output MLP + pred + cert ----------------
__global__ __launch_bounds__(256)
void k_outpath(const float* __restrict__ act, float* __restrict__ ao, float* __restrict__ bo,
               const float* __restrict__ dec_o, const int* __restrict__ oL, const int* __restrict__ oR,
               const float* __restrict__ opw1, const float* __restrict__ opb1,
               const float* __restrict__ l1g, const float* __restrict__ l1b,
               const float* __restrict__ opw2, const float* __restrict__ opb2,
               const float* __restrict__ l2g, const float* __restrict__ l2b,
               const float* __restrict__ opw3, const float* __restrict__ opb3,
               float* __restrict__ outp, int tick) {
  int b = blockIdx.x, t = threadIdx.x;
  __shared__ float red[256];
  __shared__ float syo[256], h1s[256], h2s[64];
  const float* actb = act + (size_t)b * 1024;
  float po = actb[oL[t]] * actb[oR[t]];
  float r = __expf(-fminf(fmaxf(dec_o[t], 0.f), 15.f));
  int ai = b * 256 + t;
  float av = fmaf(r, ao[ai], po);
  float bv = fmaf(r, bo[ai], 1.f);
  ao[ai] = av; bo[ai] = bv;
  syo[t] = av * rsqrtf(bv + 1e-8f);
  __syncthreads();
  float z = opb1[t];
  for (int k = 0; k < 256; ++k) z = fmaf(syo[k], opw1[k * 256 + t], z);
  float s1 = blockReduceSum(z, red);
  float s2 = blockReduceSum(z * z, red);
  float mu = s1 * (1.f / 256.f);
  float rstd = rsqrtf(s2 * (1.f / 256.f) - mu * mu + 1e-5f);
  h1s[t] = fmaxf(fmaf((z - mu) * rstd, l1g[t], l1b[t]), 0.f);
  __syncthreads();
  if (t < 64) {
    float z2 = opb2[t];
    for (int k = 0; k < 256; ++k) z2 = fmaf(h1s[k], opw2[k * 64 + t], z2);
    float a1 = z2, a2 = z2 * z2;
    #pragma unroll
    for (int o = 32; o > 0; o >>= 1) { a1 += __shfl_xor(a1, o); a2 += __shfl_xor(a2, o); }
    float mu2 = a1 * (1.f / 64.f);
    float rs2 = rsqrtf(a2 * (1.f / 64.f) - mu2 * mu2 + 1e-5f);
    h2s[t] = fmaxf(fmaf((z2 - mu2) * rs2, l2g[t], l2b[t]), 0.f);
  }
  __syncthreads();
  float zp[4];
  float mymax = -INFINITY;
  #pragma unroll
  for (int g2 = 0; g2 < 4; ++g2) {
    int j = t + g2 * 256;
    if (j < OUT_) {
      float z3 = opb3[j];
      for (int k = 0; k < 64; ++k) z3 = fmaf(h2s[k], opw3[k * OUT_ + j], z3);
      outp[(size_t)b * (OUT_ * T_) + (size_t)j * T_ + tick] = z3;
      zp[g2] = z3;
      mymax = fmaxf(mymax, z3);
    } else zp[g2] = -INFINITY;
  }
  float mx = blockReduceMax(mymax, red);
  float es = 0.f;
  #pragma unroll
  for (int g2 = 0; g2 < 4; ++g2) {
    if (t + g2 * 256 < OUT_) { zp[g2] = __expf(zp[g2] - mx); es += zp[g2]; }
    else zp[g2] = 0.f;
  }
  float S = blockReduceSum(es, red);
  float inv = 1.f / S;
  float ep = 0.f;
  #pragma unroll
  for (int g2 = 0; g2 < 4; ++g2) {
    if (t + g2 * 256 < OUT_) {
      float p = zp[g2] * inv;
      ep += p * __logf(p + 1e-10f);
    }
  }
  float ent = -blockReduceSum(ep, red);
  if (t == 0) {
    float ne = ent * (1.f / logf(1000.f));
    outp[(size_t)B_ * OUT_ * T_ + (size_t)b * 2 * T_ + tick]      = ne;
    outp[(size_t)B_ * OUT_ * T_ + (size_t)b * 2 * T_ + T_ + tick] = 1.f - ne;
  }
}

extern "C" void kernel_launch(void* const* d_in, const int* in_sizes, int n_in,
                              void* d_out, int out_size, void* d_ws, size_t ws_size,
                              hipStream_t stream) {
  (void)in_sizes; (void)n_in; (void)out_size; (void)ws_size;
  const float* x      = (const float*)d_in[0];
  const float* c1w    = (const float*)d_in[1];
  const float* bn1g   = (const float*)d_in[3];
  const float* bn1b   = (const float*)d_in[4];
  const float* c2w    = (const float*)d_in[5];
  const float* bn2g   = (const float*)d_in[7];
  const float* bn2b   = (const float*)d_in[8];
  const float* c3w    = (const float*)d_in[9];
  const float* bn3g   = (const float*)d_in[11];
  const float* bn3b   = (const float*)d_in[12];
  const float* c4w    = (const float*)d_in[13];
  const float* bn4g   = (const float*)d_in[15];
  const float* bn4b   = (const float*)d_in[16];
  const float* fc1w   = (const float*)d_in[17];
  const float* fc1b   = (const float*)d_in[18];
  const float* fc2w   = (const float*)d_in[19];
  const float* fc2b   = (const float*)d_in[20];
  const float* kvw    = (const float*)d_in[21];
  const float* kvb    = (const float*)d_in[22];
  const float* kvlg   = (const float*)d_in[23];
  const float* kvlb   = (const float*)d_in[24];
  const float* synw   = (const float*)d_in[25];
  const float* synb   = (const float*)d_in[26];
  const float* synlg  = (const float*)d_in[27];
  const float* synlb  = (const float*)d_in[28];
  const float* nlmw1  = (const float*)d_in[29];
  const float* nlmb1  = (const float*)d_in[30];
  const float* nlmw2  = (const float*)d_in[31];
  const float* nlmb2  = (const float*)d_in[32];
  const float* sact   = (const float*)d_in[33];
  const float* strc   = (const float*)d_in[34];
  const float* dec_o  = (const float*)d_in[36];
  const float* attn_inw = (const float*)d_in[39];
  const float* attn_inb = (const float*)d_in[40];
  const float* attn_ow  = (const float*)d_in[41];
  const float* attn_ob  = (const float*)d_in[42];
  const float* opw1   = (const float*)d_in[43];
  const float* opb1   = (const float*)d_in[44];
  const float* opl1g  = (const float*)d_in[45];
  const float* opl1b  = (const float*)d_in[46];
  const float* opw2   = (const float*)d_in[47];
  const float* opb2   = (const float*)d_in[48];
  const float* opl2g  = (const float*)d_in[49];
  const float* opl2b  = (const float*)d_in[50];
  const float* opw3   = (const float*)d_in[51];
  const float* opb3   = (const float*)d_in[52];
  const int*   oL     = (const int*)d_in[55];
  const int*   oR     = (const int*)d_in[56];
  float* outp = (float*)d_out;
  float* ws   = (float*)d_ws;

  // workspace layout (floats). Conv-phase liveness:
  //   conv1: reads x,           writes c1raw  [8388608, 12582912)
  //   conv2: reads c1raw,       writes c2raw  [0,        8388608)
  //   conv3: reads c2raw,       writes c3raw  [8388608, 12582912)  (c1raw dead)
  //   conv4: reads c3raw,       writes c4part [0,        4194304)  (c2raw dead; 4 x 1,048,576)
  //   bnpart/bnss live through all convs -> ABOVE 12582912.
  // Post-conv buffers alias the (now dead) conv regions. Total 12,587,136 fl = 50.3 MB.
  float* c2raw = ws;                    // 8,388,608
  float* c4part= ws;                    // 4 x 1,048,576 (after c2raw dead)
  float* c1raw = ws + 8388608;          // 4,194,304
  float* c3raw = ws + 8388608;          // 4,194,304 (after c1raw dead)
  float* part  = ws + 4194304;          // 2,097,152 (post-conv; after c4part consumed it's free too, but kept disjoint)
  float* trace = ws + 6291456;          // 2,097,152 (post-conv)
  float* act   = ws + 8388608;          // 65,536    (post-conv; c3raw dead by k_init)
  float* syncst= ws + 8454144;          // 131,072
  float* pooled= ws + 8585216;          // 16,384
  float* ench  = ws + 8601600;          // 8,192
  float* enc   = ws + 8609792;          // 32,768
  float* kvbuf = ws + 8642560;          // 32,768
  float* vhbuf = ws + 8675328;          // 32,768
  float* aout  = ws + 8708096;          // 32,768
  float* ao    = ws + 8740864;          // 16,384
  float* bo    = ws + 8757248;          // 16,384
  float* bnpart= ws + 12582912;         // 4,096
  float2* bnss = (float2*)(ws + 12587008); // 64 float2

  // ---- encoder convs (BN-apply of layer L fused into conv L+1 staging) ----
  k_conv_tiled<3,16,64,4,4,3,0,1><<<dim3(64,16),256,0,stream>>>(x, c1w, nullptr, c1raw);
  k_bn_stats<16,4096,1><<<dim3(16,32),256,0,stream>>>(c1raw, bnpart);
  k_bn_finalize<<<1,64,0,stream>>>(bnpart, 16, 32, 1.f/(float)(B_*4096), bn1g, bn1b, bnss);

  k_conv_tiled<16,32,64,4,4,16,1,1><<<dim3(64,16),256,0,stream>>>(c1raw, c2w, bnss, c2raw);
  k_bn_stats<32,4096,1><<<dim3(32,32),256,0,stream>>>(c2raw, bnpart);
  k_bn_finalize<<<1,64,0,stream>>>(bnpart, 32, 32, 1.f/(float)(B_*4096), bn2g, bn2b, bnss);

  // conv3: XV=2 -> TY=4 -> 8 y-tiles -> 512 blocks (2 blocks/CU for latency hiding)
  k_conv_tiled<32,64,32,4,2,16,2,1><<<dim3(64,8),256,0,stream>>>(c2raw, c3w, bnss, c3raw);
  k_bn_stats<64,1024,1><<<dim3(64,16),256,0,stream>>>(c3raw, bnpart);
  k_bn_finalize<<<1,64,0,stream>>>(bnpart, 64, 16, 1.f/(float)(B_*1024), bn3g, bn3b, bnss);

  // conv4: KSPLIT=4 over CIN -> 512 blocks, 4 partial outputs summed by consumers
  k_conv_tiled<64,64,16,8,2,16,2,4><<<dim3(64,2,4),256,0,stream>>>(c3raw, c4w, bnss, c4part);
  k_bn_stats<64,256,4><<<dim3(64,8),256,0,stream>>>(c4part, bnpart);
  k_bn_finalize<<<1,64,0,stream>>>(bnpart, 64, 8, 1.f/(float)(B_*256), bn4g, bn4b, bnss);

  k_avgpool_bn<<<64,256,0,stream>>>(c4part, bnss, pooled);

  // ---- encoder FC chain (split-K GEMM + fused reduce) ----
  k_gemm_part<256,256><<<dim3(8,4),256,0,stream>>>(pooled, fc1w, 256, part);
  k_fc_reduce<256,128,4,true,false><<<64,256,0,stream>>>(part, fc1b, 0, nullptr, nullptr, ench);
  k_gemm_part<128,512><<<dim3(16,2),256,0,stream>>>(ench, fc2w, 512, part);
  k_fc_reduce<512,512,2,false,false><<<64,256,0,stream>>>(part, fc2b, 0, nullptr, nullptr, enc);
  k_gemm_part<512,512><<<dim3(16,8),256,0,stream>>>(enc, kvw, 512, part);
  k_fc_reduce<512,512,8,false,true><<<64,256,0,stream>>>(part, kvb, 0, kvlg, kvlb, kvbuf);
  // vh = kv @ Wv + bv (attention softmax over single key == 1 -> q,k branches dead)
  k_gemm_part<512,512><<<dim3(16,8),256,0,stream>>>(kvbuf, attn_inw + 1024, 1536, part);
  k_fc_reduce<512,512,8,false,false><<<64,256,0,stream>>>(part, attn_inb + 1024, 0, nullptr, nullptr, vhbuf);
  k_gemm_part<512,512><<<dim3(16,8),256,0,stream>>>(vhbuf, attn_ow, 512, part);
  k_fc_reduce<512,512,8,false,false><<<64,256,0,stream>>>(part, attn_ob, 0, nullptr, nullptr, aout);
  k_gemm_part<512,2048><<<dim3(64,8),256,0,stream>>>(aout, synw, 2048, part);
  k_fc_reduce<2048,2048,8,false,false><<<64,256,0,stream>>>(part, synb, 0, nullptr, nullptr, syncst);

  k_init<<<8192,256,0,stream>>>(sact, strc, oL, oR, act, trace, ao, bo);

  // ---- recurrent ticks ----
  for (int t = 0; t < T_; ++t) {
    k_gemm_part<1024,2048><<<dim3(64,16),256,0,stream>>>(act, synw + (size_t)512 * 2048, 2048, part);
    k_syn_reduce<<<64,256,0,stream>>>(part, syncst, synlg, synlb, trace, t);
    k_nlm<<<1024,128,0,stream>>>(trace, nlmw1, nlmb1, nlmw2, nlmb2, act, t);
    k_outpath<<<64,256,0,stream>>>(act, ao, bo, dec_o, oL, oR,
                                   opw1, opb1, opl1g, opl1b,
                                   opw2, opb2, opl2g, opl2b,
                                   opw3, opb3, outp, t);
  }
}

// Round 6
// 709.193 us; speedup vs baseline: 3.8330x; 1.2866x over previous
//
#include <hip/hip_runtime.h>
#include <math.h>

// Problem constants
constexpr int B_ = 64, N_ = 1024, M_ = 32, T_ = 8;
constexpr int OUT_ = 1000, NSO_ = 256;

#define DEVFN __device__ __forceinline__

DEVFN float blockReduceSum(float v, float* buf) {
  int t = threadIdx.x;
  buf[t] = v; __syncthreads();
  for (int off = blockDim.x >> 1; off > 0; off >>= 1) {
    if (t < off) buf[t] += buf[t + off];
    __syncthreads();
  }
  float r = buf[0];
  __syncthreads();
  return r;
}

DEVFN float sigmoidf_(float x) { return 1.f / (1.f + __expf(-x)); }

// ---- block reductions for wide blocks (NW waves), shuffle + small LDS ----
template<int NW>
DEVFN float bsum(float v, float* red) {
  #pragma unroll
  for (int o = 32; o > 0; o >>= 1) v += __shfl_xor(v, o);
  int w = threadIdx.x >> 6, ln = threadIdx.x & 63;
  if (ln == 0) red[w] = v;
  __syncthreads();
  if (w == 0) {
    float x = (ln < NW) ? red[ln] : 0.f;
    #pragma unroll
    for (int o = 8; o > 0; o >>= 1) x += __shfl_xor(x, o);
    if (ln == 0) red[0] = x;
  }
  __syncthreads();
  float r = red[0];
  __syncthreads();
  return r;
}

template<int NW>
DEVFN float bmax(float v, float* red) {
  #pragma unroll
  for (int o = 32; o > 0; o >>= 1) v = fmaxf(v, __shfl_xor(v, o));
  int w = threadIdx.x >> 6, ln = threadIdx.x & 63;
  if (ln == 0) red[w] = v;
  __syncthreads();
  if (w == 0) {
    float x = (ln < NW) ? red[ln] : -INFINITY;
    #pragma unroll
    for (int o = 8; o > 0; o >>= 1) x = fmaxf(x, __shfl_xor(x, o));
    if (ln == 0) red[0] = x;
  }
  __syncthreads();
  float r = red[0];
  __syncthreads();
  return r;
}

// ---------------- tiled conv 3x3 SAME, NCHW, input staged in LDS ----------------
template<int CIN, int COUT, int HW, int TY, int XV, int CICH, int MODE, int KSPLIT>
__global__ __launch_bounds__(256)
void k_conv_tiled(const float* __restrict__ in, const float* __restrict__ wgl,
                  const float2* __restrict__ ssin, float* __restrict__ outp) {
  constexpr int XQ = HW / XV;
  constexpr int NCG = 4;
  constexpr int CPT = COUT / NCG;
  constexpr int PADW = HW + 8;
  constexpr int NROW = TY + 2;
  constexpr int CINB = CIN / KSPLIT;
  constexpr int NCH = CINB / CICH;
  static_assert(XQ * TY == 64, "spatial threads per co-group must be 64");
  __shared__ __align__(16) float ins[CICH][NROW][PADW];

  const int b   = blockIdx.x;
  const int y0  = blockIdx.y * TY;
  const int ks  = (KSPLIT > 1) ? blockIdx.z : 0;
  const int tid = threadIdx.x;
  const int sp  = tid & 63;
  const int cg  = __builtin_amdgcn_readfirstlane(tid >> 6);
  const int xq  = sp % XQ;
  const int yr  = sp / XQ;
  const int x0  = xq * XV;

  float acc[CPT][XV];
  #pragma unroll
  for (int j = 0; j < CPT; ++j)
    #pragma unroll
    for (int k = 0; k < XV; ++k) acc[j][k] = 0.f;

  for (int ch = 0; ch < NCH; ++ch) {
    const int ci0 = ks * CINB + ch * CICH;
    __syncthreads();
    constexpr int NEL = CICH * NROW * PADW;
    for (int i = tid; i < NEL; i += 256) {
      int col = i % PADW;
      int row = (i / PADW) % NROW;
      int ci  = i / (PADW * NROW);
      int gx = col - 4;
      int gy = y0 + row - 1;
      float v = 0.f;
      if (gx >= 0 && gx < HW && gy >= 0 && gy < HW) {
        if (MODE == 0) {
          v = in[((size_t)(b * CIN + ci0 + ci) * HW + gy) * HW + gx];
        } else if (MODE == 1) {
          float2 s = ssin[ci0 + ci];
          v = fmaxf(fmaf(in[((size_t)(b * CIN + ci0 + ci) * HW + gy) * HW + gx], s.x, s.y), 0.f);
        } else {
          float2 s = ssin[ci0 + ci];
          const float* p = in + ((size_t)(b * CIN + ci0 + ci) * (2 * HW) + 2 * gy) * (2 * HW) + 2 * gx;
          float v0 = fmaf(p[0],          s.x, s.y);
          float v1 = fmaf(p[1],          s.x, s.y);
          float v2 = fmaf(p[2 * HW],     s.x, s.y);
          float v3 = fmaf(p[2 * HW + 1], s.x, s.y);
          v = fmaxf(fmaxf(fmaxf(v0, v1), fmaxf(v2, v3)), 0.f);
        }
      }
      ins[ci][row][col] = v;
    }
    __syncthreads();

    for (int ci = 0; ci < CICH; ++ci) {
      const float* wci = wgl + ((size_t)(cg * CPT) * CIN + (ci0 + ci)) * 9;
      #pragma unroll
      for (int dy = 0; dy < 3; ++dy) {
        const float* r = &ins[ci][yr + dy][x0 + 4];
        float win[XV + 2];
        win[0] = r[-1];
        if constexpr (XV == 4) {
          float4 m = *reinterpret_cast<const float4*>(r);
          win[1] = m.x; win[2] = m.y; win[3] = m.z; win[4] = m.w;
        } else {
          float2 m = *reinterpret_cast<const float2*>(r);
          win[1] = m.x; win[2] = m.y;
        }
        win[XV + 1] = r[XV];
        #pragma unroll
        for (int j = 0; j < CPT; ++j) {
          const float* wj = wci + (size_t)j * CIN * 9 + dy * 3;
          float w0 = wj[0], w1 = wj[1], w2 = wj[2];
          #pragma unroll
          for (int k = 0; k < XV; ++k)
            acc[j][k] = fmaf(win[k], w0, fmaf(win[k + 1], w1, fmaf(win[k + 2], w2, acc[j][k])));
        }
      }
    }
  }

  const size_t pofs = (size_t)ks * B_ * COUT * HW * HW;
  #pragma unroll
  for (int j = 0; j < CPT; ++j) {
    float* op = outp + pofs + (((size_t)b * COUT + cg * CPT + j) * HW + y0 + yr) * HW + x0;
    if constexpr (XV == 4)
      *reinterpret_cast<float4*>(op) = make_float4(acc[j][0], acc[j][1], acc[j][2], acc[j][3]);
    else
      *reinterpret_cast<float2*>(op) = make_float2(acc[j][0], acc[j][1]);
  }
}

// ---------------- BatchNorm (train mode) statistics, over sum of NS partials ----------------
template<int C, int HW2, int NS>
__global__ __launch_bounds__(256)
void k_bn_stats(const float* __restrict__ x, float* __restrict__ part) {
  int c = blockIdx.x, s = blockIdx.y, ns = gridDim.y;
  const int Npc = B_ * HW2;
  constexpr size_t PSTR = (size_t)B_ * C * HW2;
  float s1 = 0.f, s2 = 0.f;
  for (int ii = s * 256 + threadIdx.x; ii < Npc; ii += ns * 256) {
    int b = ii / HW2, pos = ii % HW2;
    size_t base = ((size_t)b * C + c) * HW2 + pos;
    float v = x[base];
    #pragma unroll
    for (int q = 1; q < NS; ++q) v += x[base + q * PSTR];
    s1 += v; s2 += v * v;
  }
  __shared__ float r1[256], r2[256];
  r1[threadIdx.x] = s1; r2[threadIdx.x] = s2; __syncthreads();
  for (int off = 128; off > 0; off >>= 1) {
    if (threadIdx.x < off) { r1[threadIdx.x] += r1[threadIdx.x + off]; r2[threadIdx.x] += r2[threadIdx.x + off]; }
    __syncthreads();
  }
  if (threadIdx.x == 0) {
    part[(c * ns + s) * 2 + 0] = r1[0];
    part[(c * ns + s) * 2 + 1] = r2[0];
  }
}

__global__ void k_bn_finalize(const float* __restrict__ part, int C, int ns, float inv_n,
                              const float* __restrict__ g, const float* __restrict__ bb,
                              float2* __restrict__ ss) {
  int c = threadIdx.x;
  if (c >= C) return;
  float s1 = 0.f, s2 = 0.f;
  for (int s = 0; s < ns; ++s) { s1 += part[(c * ns + s) * 2]; s2 += part[(c * ns + s) * 2 + 1]; }
  float m = s1 * inv_n;
  float var = s2 * inv_n - m * m;
  float rstd = rsqrtf(var + 1e-5f);
  float sc = g[c] * rstd;
  ss[c] = make_float2(sc, bb[c] - m * sc);
}

// ---------------- (sum 4 partials) + bn4 + relu + adaptive avg pool fused ----------------
__global__ __launch_bounds__(256)
void k_avgpool_bn(const float* __restrict__ x, const float2* __restrict__ ss,
                  float* __restrict__ outp) {
  constexpr size_t PSTR = (size_t)B_ * 64 * 256;
  int idx = blockIdx.x * 256 + threadIdx.x;
  if (idx >= B_ * 256) return;
  int b = idx >> 8;
  int r = idx & 255;
  int c = r >> 2, i = (r >> 1) & 1, j = r & 1;
  float2 s = ss[c];
  const float* p = x + ((size_t)(b * 64 + c) * 16 + i * 8) * 16 + j * 8;
  float sum = 0.f;
  #pragma unroll
  for (int yy = 0; yy < 8; ++yy)
    #pragma unroll
    for (int xx = 0; xx < 8; ++xx) {
      size_t o = yy * 16 + xx;
      float v = p[o] + p[o + PSTR] + p[o + 2 * PSTR] + p[o + 3 * PSTR];
      sum += fmaxf(fmaf(v, s.x, s.y), 0.f);
    }
  outp[idx] = sum * (1.f / 64.f);
}

// ---------------- split-K GEMM: A(64 x K) @ W(K x NOUT) -> partials ----------------
template<int K, int NOUT>
__global__ __launch_bounds__(256)
void k_gemm_part(const float* __restrict__ A, const float* __restrict__ W, int ldw,
                 float* __restrict__ part) {
  int jt = blockIdx.x, ks = blockIdx.y;
  int k0 = ks * 64;
  __shared__ float As[64][65];
  for (int i = threadIdx.x; i < 4096; i += 256) {
    int r = i >> 6, c = i & 63;
    As[r][c] = A[(size_t)r * K + k0 + c];
  }
  __syncthreads();
  int jsub = threadIdx.x & 31;
  int bg = threadIdx.x >> 5;
  int j = jt * 32 + jsub;
  float acc[8] = {0.f, 0.f, 0.f, 0.f, 0.f, 0.f, 0.f, 0.f};
  const float* wp = W + (size_t)k0 * ldw + j;
  #pragma unroll 8
  for (int kk = 0; kk < 64; ++kk) {
    float w = wp[(size_t)kk * ldw];
    #pragma unroll
    for (int r = 0; r < 8; ++r) acc[r] = fmaf(As[bg * 8 + r][kk], w, acc[r]);
  }
  float* pp = part + (size_t)ks * 64 * NOUT + j;
  #pragma unroll
  for (int r = 0; r < 8; ++r) pp[(size_t)(bg * 8 + r) * NOUT] = acc[r];
}

// ---------------- reduce partials + bias (+GLU) (+LN) ----------------
template<int NOUT, int NO_FIN, int KS, bool GLU_, bool LN_>
__global__ __launch_bounds__(256)
void k_fc_reduce(const float* __restrict__ part, const float* __restrict__ bias, int bstride,
                 const float* __restrict__ lng, const float* __restrict__ lnb,
                 float* __restrict__ outp) {
  constexpr int R = (NO_FIN + 255) / 256;
  int b = blockIdx.x, t = threadIdx.x;
  const float* bp = bias + (size_t)b * bstride;
  float v[R];
  #pragma unroll
  for (int r = 0; r < R; ++r) {
    int j = t + r * 256;
    if (j < NO_FIN) {
      float za = bp[j];
      float zb = GLU_ ? bp[j + NO_FIN] : 0.f;
      #pragma unroll
      for (int ks = 0; ks < KS; ++ks) {
        const float* pr = part + ((size_t)ks * 64 + b) * NOUT;
        za += pr[j];
        if (GLU_) zb += pr[j + NO_FIN];
      }
      v[r] = GLU_ ? za * sigmoidf_(zb) : za;
    } else v[r] = 0.f;
  }
  if (LN_) {
    __shared__ float red[256];
    float s1 = 0.f, s2 = 0.f;
    #pragma unroll
    for (int r = 0; r < R; ++r) { s1 += v[r]; s2 += v[r] * v[r]; }
    s1 = blockReduceSum(s1, red);
    s2 = blockReduceSum(s2, red);
    float mu = s1 / (float)NO_FIN;
    float rstd = rsqrtf(s2 / (float)NO_FIN - mu * mu + 1e-5f);
    #pragma unroll
    for (int r = 0; r < R; ++r) {
      int j = t + r * 256;
      if (j < NO_FIN) outp[(size_t)b * NO_FIN + j] = fmaf((v[r] - mu) * rstd, lng[j], lnb[j]);
    }
  } else {
    #pragma unroll
    for (int r = 0; r < R; ++r) {
      int j = t + r * 256;
      if (j < NO_FIN) outp[(size_t)b * NO_FIN + j] = v[r];
    }
  }
}

// ---------------- per-tick: syn reduce (1024 thr) = partials + syncst -> GLU -> LN -> trace ----------------
__global__ __launch_bounds__(1024)
void k_syn_reduce(const float* __restrict__ part, const float* __restrict__ syncst,
                  const float* __restrict__ g, const float* __restrict__ bb,
                  float* __restrict__ trace, int slot) {
  int b = blockIdx.x, t = threadIdx.x;   // t = output index j (0..1023)
  __shared__ float red[16];
  float za = syncst[b * 2048 + t];
  float zb = syncst[b * 2048 + 1024 + t];
  #pragma unroll
  for (int ks = 0; ks < 16; ++ks) {
    const float* pr = part + ((size_t)ks * 64 + b) * 2048;
    za += pr[t];
    zb += pr[t + 1024];
  }
  float v = za * sigmoidf_(zb);
  float s1 = bsum<16>(v, red);
  float s2 = bsum<16>(v * v, red);
  float mu = s1 * (1.f / 1024.f);
  float rstd = rsqrtf(s2 * (1.f / 1024.f) - mu * mu + 1e-5f);
  trace[((size_t)b * N_ + t) * M_ + slot] = fmaf((v - mu) * rstd, g[t], bb[t]);
}

// ---------------- recurrent state init ----------------
__global__ __launch_bounds__(256)
void k_init(const float* __restrict__ sa, const float* __restrict__ st,
            const int* __restrict__ oL, const int* __restrict__ oR,
            float* __restrict__ act, float* __restrict__ trace,
            float* __restrict__ ao, float* __restrict__ bo) {
  int idx = blockIdx.x * 256 + threadIdx.x;
  if (idx < B_ * N_ * M_) trace[idx] = st[idx % (N_ * M_)];
  if (idx < B_ * N_)      act[idx]   = sa[idx % N_];
  if (idx < B_ * NSO_) {
    int i = idx % NSO_;
    ao[idx] = sa[oL[i]] * sa[oR[i]];
    bo[idx] = 1.f;
  }
}

// ---------------- per-tick: per-neuron private MLP (256 thr: 128 cols x 2 batch-halves) ----------------
__global__ __launch_bounds__(256)
void k_nlm(const float* __restrict__ trace, const float* __restrict__ w1,
           const float* __restrict__ b1, const float* __restrict__ w2,
           const float* __restrict__ b2, float* __restrict__ act, int tick) {
  int n = blockIdx.x, t = threadIdx.x;
  int c = t & 127;          // GLU column
  int h = t >> 7;           // batch half
  __shared__ float tr[64][32];
  __shared__ float hid[128][65];
  __shared__ float comb[4][64];
  for (int k = t; k < 64 * 32; k += 256) {
    tr[k >> 5][k & 31] = trace[((size_t)(k >> 5) * N_ + n) * M_ + (k & 31)];
  }
  const float* wp = w1 + (size_t)n * (M_ * 256);
  float wa[32], wb[32];
  #pragma unroll
  for (int ms = 0; ms < 32; ++ms) {
    int m = (ms - tick - 1) & 31;   // ring: physical slot ms holds logical m
    wa[ms] = wp[m * 256 + c];
    wb[ms] = wp[m * 256 + 128 + c];
  }
  float ba = b1[n * 256 + c];
  float bgt = b1[n * 256 + 128 + c];
  float w2v = w2[n * 128 + c];
  __syncthreads();
  for (int b = h * 32; b < h * 32 + 32; ++b) {
    const float4* trb = reinterpret_cast<const float4*>(&tr[b][0]);
    float za = ba, zb = bgt;
    #pragma unroll
    for (int q = 0; q < 8; ++q) {
      float4 v = trb[q];
      za = fmaf(v.x, wa[4*q+0], za); zb = fmaf(v.x, wb[4*q+0], zb);
      za = fmaf(v.y, wa[4*q+1], za); zb = fmaf(v.y, wb[4*q+1], zb);
      za = fmaf(v.z, wa[4*q+2], za); zb = fmaf(v.z, wb[4*q+2], zb);
      za = fmaf(v.w, wa[4*q+3], za); zb = fmaf(v.w, wb[4*q+3], zb);
    }
    hid[c][b] = za * sigmoidf_(zb) * w2v;
  }
  __syncthreads();
  int bb2 = t & 63, q = t >> 6;    // q = column-quarter (32 cols)
  float s = 0.f;
  #pragma unroll 8
  for (int cc = 0; cc < 32; ++cc) s += hid[q * 32 + cc][bb2];
  comb[q][bb2] = s;
  __syncthreads();
  if (t < 64)
    act[(size_t)t * N_ + n] = comb[0][t] + comb[1][t] + comb[2][t] + comb[3][t] + b2[n];
}

// ---------------- per-tick: sync_o + output MLP + pred + cert (1024 thr, split-K phases) ----------------
__global__ __launch_bounds__(1024)
void k_outpath(const float* __restrict__ act, float* __restrict__ ao, float* __restrict__ bo,
               const float* __restrict__ dec_o, const int* __restrict__ oL, const int* __restrict__ oR,
               const float* __restrict__ opw1, const float* __restrict__ opb1,
               const float* __restrict__ l1g, const float* __restrict__ l1b,
               const float* __restrict__ opw2, const float* __restrict__ opb2,
               const float* __restrict__ l2g, const float* __restrict__ l2b,
               const float* __restrict__ opw3, const float* __restrict__ opb3,
               float* __restrict__ outp, int tick) {
  int b = blockIdx.x, t = threadIdx.x;
  __shared__ float red[16];
  __shared__ float syo[256], h1s[256], h2s[64];
  __shared__ float zp1[4][256];
  __shared__ float zp2[16][64];
  const float* actb = act + (size_t)b * 1024;

  // sync_o update (one thread per pair)
  if (t < 256) {
    float po = actb[oL[t]] * actb[oR[t]];
    float r = __expf(-fminf(fmaxf(dec_o[t], 0.f), 15.f));
    int ai = b * 256 + t;
    float av = fmaf(r, ao[ai], po);
    float bv = fmaf(r, bo[ai], 1.f);
    ao[ai] = av; bo[ai] = bv;
    syo[t] = av * rsqrtf(bv + 1e-8f);
  }
  __syncthreads();

  // h1: z[j] = sum_k syo[k]*opw1[k][j], split over 4 k-slices
  {
    int j = t & 255, ks = t >> 8;
    float z = 0.f;
    const float* wcol = opw1 + j;
    #pragma unroll 8
    for (int k = ks * 64; k < ks * 64 + 64; ++k) z = fmaf(syo[k], wcol[k * 256], z);
    zp1[ks][j] = z;
  }
  __syncthreads();
  float h1v = 0.f;
  if (t < 256) h1v = zp1[0][t] + zp1[1][t] + zp1[2][t] + zp1[3][t] + opb1[t];
  float s1 = bsum<16>(t < 256 ? h1v : 0.f, red);
  float s2 = bsum<16>(t < 256 ? h1v * h1v : 0.f, red);
  if (t < 256) {
    float mu = s1 * (1.f / 256.f);
    float rstd = rsqrtf(s2 * (1.f / 256.f) - mu * mu + 1e-5f);
    h1s[t] = fmaxf(fmaf((h1v - mu) * rstd, l1g[t], l1b[t]), 0.f);
  }
  __syncthreads();

  // h2: z[j] = sum_k h1s[k]*opw2[k][j], split over 16 k-slices of 16
  {
    int j = t & 63, ks = t >> 6;
    float z = 0.f;
    const float* wcol = opw2 + j;
    #pragma unroll
    for (int k = ks * 16; k < ks * 16 + 16; ++k) z = fmaf(h1s[k], wcol[k * 64], z);
    zp2[ks][j] = z;
  }
  __syncthreads();
  if (t < 64) {
    float z2 = opb2[t];
    #pragma unroll
    for (int ks = 0; ks < 16; ++ks) z2 += zp2[ks][t];
    float a1 = z2, a2 = z2 * z2;
    #pragma unroll
    for (int o = 32; o > 0; o >>= 1) { a1 += __shfl_xor(a1, o); a2 += __shfl_xor(a2, o); }
    float mu2 = a1 * (1.f / 64.f);
    float rs2 = rsqrtf(a2 * (1.f / 64.f) - mu2 * mu2 + 1e-5f);
    h2s[t] = fmaxf(fmaf((z2 - mu2) * rs2, l2g[t], l2b[t]), 0.f);
  }
  __syncthreads();

  // pred: one column per thread (t < 1000)
  float z3 = 0.f;
  if (t < OUT_) {
    z3 = opb3[t];
    const float* wcol = opw3 + t;
    #pragma unroll 8
    for (int k = 0; k < 64; ++k) z3 = fmaf(h2s[k], wcol[k * OUT_], z3);
    outp[(size_t)b * (OUT_ * T_) + (size_t)t * T_ + tick] = z3;
  }
  float mx = bmax<16>(t < OUT_ ? z3 : -INFINITY, red);
  float e = (t < OUT_) ? __expf(z3 - mx) : 0.f;
  float S = bsum<16>(e, red);
  float inv = 1.f / S;
  float ep = 0.f;
  if (t < OUT_) {
    float p = e * inv;
    ep = p * __logf(p + 1e-10f);
  }
  float ent = -bsum<16>(ep, red);
  if (t == 0) {
    float ne = ent * (1.f / logf(1000.f));
    outp[(size_t)B_ * OUT_ * T_ + (size_t)b * 2 * T_ + tick]      = ne;
    outp[(size_t)B_ * OUT_ * T_ + (size_t)b * 2 * T_ + T_ + tick] = 1.f - ne;
  }
}

extern "C" void kernel_launch(void* const* d_in, const int* in_sizes, int n_in,
                              void* d_out, int out_size, void* d_ws, size_t ws_size,
                              hipStream_t stream) {
  (void)in_sizes; (void)n_in; (void)out_size; (void)ws_size;
  const float* x      = (const float*)d_in[0];
  const float* c1w    = (const float*)d_in[1];
  const float* bn1g   = (const float*)d_in[3];
  const float* bn1b   = (const float*)d_in[4];
  const float* c2w    = (const float*)d_in[5];
  const float* bn2g   = (const float*)d_in[7];
  const float* bn2b   = (const float*)d_in[8];
  const float* c3w    = (const float*)d_in[9];
  const float* bn3g   = (const float*)d_in[11];
  const float* bn3b   = (const float*)d_in[12];
  const float* c4w    = (const float*)d_in[13];
  const float* bn4g   = (const float*)d_in[15];
  const float* bn4b   = (const float*)d_in[16];
  const float* fc1w   = (const float*)d_in[17];
  const float* fc1b   = (const float*)d_in[18];
  const float* fc2w   = (const float*)d_in[19];
  const float* fc2b   = (const float*)d_in[20];
  const float* kvw    = (const float*)d_in[21];
  const float* kvb    = (const float*)d_in[22];
  const float* kvlg   = (const float*)d_in[23];
  const float* kvlb   = (const float*)d_in[24];
  const float* synw   = (const float*)d_in[25];
  const float* synb   = (const float*)d_in[26];
  const float* synlg  = (const float*)d_in[27];
  const float* synlb  = (const float*)d_in[28];
  const float* nlmw1  = (const float*)d_in[29];
  const float* nlmb1  = (const float*)d_in[30];
  const float* nlmw2  = (const float*)d_in[31];
  const float* nlmb2  = (const float*)d_in[32];
  const float* sact   = (const float*)d_in[33];
  const float* strc   = (const float*)d_in[34];
  const float* dec_o  = (const float*)d_in[36];
  const float* attn_inw = (const float*)d_in[39];
  const float* attn_inb = (const float*)d_in[40];
  const float* attn_ow  = (const float*)d_in[41];
  const float* attn_ob  = (const float*)d_in[42];
  const float* opw1   = (const float*)d_in[43];
  const float* opb1   = (const float*)d_in[44];
  const float* opl1g  = (const float*)d_in[45];
  const float* opl1b  = (const float*)d_in[46];
  const float* opw2   = (const float*)d_in[47];
  const float* opb2   = (const float*)d_in[48];
  const float* opl2g  = (const float*)d_in[49];
  const float* opl2b  = (const float*)d_in[50];
  const float* opw3   = (const float*)d_in[51];
  const float* opb3   = (const float*)d_in[52];
  const int*   oL     = (const int*)d_in[55];
  const int*   oR     = (const int*)d_in[56];
  float* outp = (float*)d_out;
  float* ws   = (float*)d_ws;

  // workspace layout (floats); bnpart/bnss live through convs -> above 12582912.
  float* c2raw = ws;                    // 8,388,608
  float* c4part= ws;                    // 4 x 1,048,576 (after c2raw dead)
  float* c1raw = ws + 8388608;          // 4,194,304
  float* c3raw = ws + 8388608;          // 4,194,304 (after c1raw dead)
  float* part  = ws + 4194304;          // 2,097,152 (post-conv)
  float* trace = ws + 6291456;          // 2,097,152 (post-conv)
  float* act   = ws + 8388608;          // 65,536    (post-conv)
  float* syncst= ws + 8454144;          // 131,072
  float* pooled= ws + 8585216;          // 16,384
  float* ench  = ws + 8601600;          // 8,192
  float* enc   = ws + 8609792;          // 32,768
  float* kvbuf = ws + 8642560;          // 32,768
  float* vhbuf = ws + 8675328;          // 32,768
  float* aout  = ws + 8708096;          // 32,768
  float* ao    = ws + 8740864;          // 16,384
  float* bo    = ws + 8757248;          // 16,384
  float* bnpart= ws + 12582912;         // 4,096
  float2* bnss = (float2*)(ws + 12587008); // 64 float2

  // ---- encoder convs (BN-apply of layer L fused into conv L+1 staging) ----
  k_conv_tiled<3,16,64,4,4,3,0,1><<<dim3(64,16),256,0,stream>>>(x, c1w, nullptr, c1raw);
  k_bn_stats<16,4096,1><<<dim3(16,32),256,0,stream>>>(c1raw, bnpart);
  k_bn_finalize<<<1,64,0,stream>>>(bnpart, 16, 32, 1.f/(float)(B_*4096), bn1g, bn1b, bnss);

  k_conv_tiled<16,32,64,4,4,16,1,1><<<dim3(64,16),256,0,stream>>>(c1raw, c2w, bnss, c2raw);
  k_bn_stats<32,4096,1><<<dim3(32,32),256,0,stream>>>(c2raw, bnpart);
  k_bn_finalize<<<1,64,0,stream>>>(bnpart, 32, 32, 1.f/(float)(B_*4096), bn2g, bn2b, bnss);

  k_conv_tiled<32,64,32,4,2,16,2,1><<<dim3(64,8),256,0,stream>>>(c2raw, c3w, bnss, c3raw);
  k_bn_stats<64,1024,1><<<dim3(64,16),256,0,stream>>>(c3raw, bnpart);
  k_bn_finalize<<<1,64,0,stream>>>(bnpart, 64, 16, 1.f/(float)(B_*1024), bn3g, bn3b, bnss);

  k_conv_tiled<64,64,16,8,2,16,2,4><<<dim3(64,2,4),256,0,stream>>>(c3raw, c4w, bnss, c4part);
  k_bn_stats<64,256,4><<<dim3(64,8),256,0,stream>>>(c4part, bnpart);
  k_bn_finalize<<<1,64,0,stream>>>(bnpart, 64, 8, 1.f/(float)(B_*256), bn4g, bn4b, bnss);

  k_avgpool_bn<<<64,256,0,stream>>>(c4part, bnss, pooled);

  // ---- encoder FC chain (split-K GEMM + fused reduce) ----
  k_gemm_part<256,256><<<dim3(8,4),256,0,stream>>>(pooled, fc1w, 256, part);
  k_fc_reduce<256,128,4,true,false><<<64,256,0,stream>>>(part, fc1b, 0, nullptr, nullptr, ench);
  k_gemm_part<128,512><<<dim3(16,2),256,0,stream>>>(ench, fc2w, 512, part);
  k_fc_reduce<512,512,2,false,false><<<64,256,0,stream>>>(part, fc2b, 0, nullptr, nullptr, enc);
  k_gemm_part<512,512><<<dim3(16,8),256,0,stream>>>(enc, kvw, 512, part);
  k_fc_reduce<512,512,8,false,true><<<64,256,0,stream>>>(part, kvb, 0, kvlg, kvlb, kvbuf);
  // vh = kv @ Wv + bv (attention softmax over single key == 1 -> q,k branches dead)
  k_gemm_part<512,512><<<dim3(16,8),256,0,stream>>>(kvbuf, attn_inw + 1024, 1536, part);
  k_fc_reduce<512,512,8,false,false><<<64,256,0,stream>>>(part, attn_inb + 1024, 0, nullptr, nullptr, vhbuf);
  k_gemm_part<512,512><<<dim3(16,8),256,0,stream>>>(vhbuf, attn_ow, 512, part);
  k_fc_reduce<512,512,8,false,false><<<64,256,0,stream>>>(part, attn_ob, 0, nullptr, nullptr, aout);
  k_gemm_part<512,2048><<<dim3(64,8),256,0,stream>>>(aout, synw, 2048, part);
  k_fc_reduce<2048,2048,8,false,false><<<64,256,0,stream>>>(part, synb, 0, nullptr, nullptr, syncst);

  k_init<<<8192,256,0,stream>>>(sact, strc, oL, oR, act, trace, ao, bo);

  // ---- recurrent ticks ----
  for (int t = 0; t < T_; ++t) {
    k_gemm_part<1024,2048><<<dim3(64,16),256,0,stream>>>(act, synw + (size_t)512 * 2048, 2048, part);
    k_syn_reduce<<<64,1024,0,stream>>>(part, syncst, synlg, synlb, trace, t);
    k_nlm<<<1024,256,0,stream>>>(trace, nlmw1, nlmb1, nlmw2, nlmb2, act, t);
    k_outpath<<<64,1024,0,stream>>>(act, ao, bo, dec_o, oL, oR,
                                    opw1, opb1, opl1g, opl1b,
                                    opw2, opb2, opl2g, opl2b,
                                    opw3, opb3, outp, t);
  }
}